// Round 3
// baseline (205.255 us; speedup 1.0000x reference)
//
#include <hip/hip_runtime.h>
#include <hip/hip_bf16.h>

// AttentionBlock: GroupNorm -> QKV -> 4-head attention (S=4096, D=64) -> out proj -> +residual
// B=4, C=256, H=W=64, S=4096, N_GROUPS=32, N_HEADS=4, D_K=64

typedef __attribute__((ext_vector_type(8))) short short8;   // 8 bf16 (4 VGPRs) MFMA A/B frag
typedef __attribute__((ext_vector_type(4))) float f32x4;    // 16x16 MFMA C/D frag
typedef __attribute__((ext_vector_type(16))) float f32x16;  // 32x32 MFMA C/D frag

__device__ __forceinline__ unsigned short f2bf(float f) {
    union { float f; unsigned u; } v; v.f = f;
    unsigned r = v.u + 0x7FFF + ((v.u >> 16) & 1);
    return (unsigned short)(r >> 16);
}

__device__ __forceinline__ unsigned cvt_pk_bf16(float lo, float hi) {
    unsigned r;
    asm("v_cvt_pk_bf16_f32 %0, %1, %2" : "=v"(r) : "v"(lo), "v"(hi));
    return r;
}

__device__ __forceinline__ void permswap(unsigned &x, unsigned &y) {
    // x' = [x_lo | y_lo], y' = [x_hi | y_hi]   (vdst hi-half <-> vsrc lo-half)
    asm("v_permlane32_swap_b32 %0, %1" : "+v"(x), "+v"(y));
}

__device__ __forceinline__ float fexp2(float x) {   // D = 2^S0
    float r;
    asm("v_exp_f32 %0, %1" : "=v"(r) : "v"(x));
    return r;
}

__device__ __forceinline__ void gl_lds16(const void* g, void* l) {
    __builtin_amdgcn_global_load_lds(
        (const __attribute__((address_space(1))) void*)(g),
        (__attribute__((address_space(3))) void*)(l), 16, 0, 0);
}

__device__ __forceinline__ f32x16 fzero16() {
    f32x16 z;
    #pragma unroll
    for (int i = 0; i < 16; ++i) z[i] = 0.f;
    return z;
}

// ---------------- GroupNorm stats: one block per (b,g), 8ch*4096 = 32768 elems ----------------
__global__ __launch_bounds__(1024) void k_gn_stats(const float* __restrict__ x,
                                                   float* __restrict__ stats) {
    int bg = blockIdx.x;                       // b*32+g ; group channels contiguous
    const float4* xp = (const float4*)(x + bg * 32768);
    float s1 = 0.f, s2 = 0.f;
    for (int i = threadIdx.x; i < 8192; i += 1024) {
        float4 v = xp[i];
        s1 += v.x + v.y + v.z + v.w;
        s2 += v.x*v.x + v.y*v.y + v.z*v.z + v.w*v.w;
    }
    #pragma unroll
    for (int off = 32; off; off >>= 1) {
        s1 += __shfl_down(s1, off);
        s2 += __shfl_down(s2, off);
    }
    __shared__ float r1[16], r2[16];
    int wid = threadIdx.x >> 6;
    if ((threadIdx.x & 63) == 0) { r1[wid] = s1; r2[wid] = s2; }
    __syncthreads();
    if (threadIdx.x == 0) {
        float a = 0.f, b = 0.f;
        #pragma unroll
        for (int i = 0; i < 16; ++i) { a += r1[i]; b += r2[i]; }
        float mean = a * (1.f/32768.f);
        float var  = b * (1.f/32768.f) - mean*mean;
        stats[bg*2]   = mean;
        stats[bg*2+1] = rsqrtf(var + 1e-5f);
    }
}

// ------------- convert + transpose weights to bf16 [N][K] so B-frags are contiguous -------------
__global__ void k_cvt_w(const float* __restrict__ wqkv, const float* __restrict__ wout,
                        unsigned short* __restrict__ wqkvT, unsigned short* __restrict__ woutT) {
    int i = blockIdx.x * 256 + threadIdx.x;
    if (i < 196608) {                       // w_qkv [256][768] -> [768][256]
        int k = i / 768, n = i - k * 768;
        wqkvT[n*256 + k] = f2bf(wqkv[i]);
    }
    if (i < 65536) {                        // w_out [256][256] -> [256][256]^T
        int k = i >> 8, n = i & 255;
        woutT[n*256 + k] = f2bf(wout[i]);
    }
}

// ------- normalize + transpose: x[b][c][s] fp32 -> h[b][s][c] bf16 via 64x64 LDS tile -------
__global__ __launch_bounds__(256) void k_gn_norm(
    const float* __restrict__ x, const float* __restrict__ gamma,
    const float* __restrict__ beta, const float* __restrict__ stats,
    unsigned short* __restrict__ h) {
    __shared__ unsigned short t[64][72];          // pad 8 -> decent bank spread
    int s0 = blockIdx.x * 64, c0 = blockIdx.y * 64, b = blockIdx.z;
    int tid = threadIdx.x;
    int sl = (tid & 15) * 4;                      // float4 along s
    int cr = tid >> 4;
    #pragma unroll
    for (int p = 0; p < 4; ++p) {
        int c = c0 + cr + p * 16;
        float4 v = *(const float4*)&x[(b*256 + c)*4096 + s0 + sl];
        int sg = (b*32 + (c >> 3)) * 2;
        float mean = stats[sg], rstd = stats[sg+1];
        float sa = rstd * gamma[c];
        float sb = beta[c] - mean * sa;
        ushort4 pk;
        pk.x = f2bf(v.x*sa + sb); pk.y = f2bf(v.y*sa + sb);
        pk.z = f2bf(v.z*sa + sb); pk.w = f2bf(v.w*sa + sb);
        *(ushort4*)&t[cr + p*16][sl] = pk;
    }
    __syncthreads();
    int sr = tid >> 2;                            // 0..63 (s row)
    int cc = (tid & 3) * 16;                      // 16 channels per thread
    unsigned rr[8];
    #pragma unroll
    for (int j = 0; j < 8; ++j)
        rr[j] = (unsigned)t[cc + 2*j][sr] | ((unsigned)t[cc + 2*j + 1][sr] << 16);
    unsigned short* hp = &h[(b*4096 + s0 + sr)*256 + c0];
    *(uint4*)&hp[cc]     = make_uint4(rr[0], rr[1], rr[2], rr[3]);
    *(uint4*)&hp[cc + 8] = make_uint4(rr[4], rr[5], rr[6], rr[7]);
}

// ---------------- QKV GEMM: h[16384][256] @ wqkvT -> q,k [bh][S][64], vT [bh][64][S] ----------------
// Q gets 0.125 * log2(e) folded in (attention softmax runs in exp2 domain).
__global__ __launch_bounds__(256) void k_qkv(
    const unsigned short* __restrict__ h, const unsigned short* __restrict__ wT,
    const float* __restrict__ bqkv,
    unsigned short* __restrict__ q, unsigned short* __restrict__ kk,
    unsigned short* __restrict__ vT) {
    int mt = blockIdx.x, head = blockIdx.y;
    int tid = threadIdx.x;
    int wid = tid >> 6, lane = tid & 63;
    int g = lane >> 4, li = lane & 15;
    int m0 = mt * 64 + wid * 16;
    int row = m0 + li;
    f32x4 acc[12];
    #pragma unroll
    for (int nt = 0; nt < 12; ++nt) acc[nt] = (f32x4){0.f,0.f,0.f,0.f};
    #pragma unroll
    for (int kt = 0; kt < 8; ++kt) {
        short8 a = *(const short8*)&h[row*256 + kt*32 + g*8];
        #pragma unroll
        for (int nt = 0; nt < 12; ++nt) {
            int n = head*192 + nt*16 + li;
            short8 b = *(const short8*)&wT[n*256 + kt*32 + g*8];
            acc[nt] = __builtin_amdgcn_mfma_f32_16x16x32_bf16(a, b, acc[nt], 0, 0, 0);
        }
    }
    int b = m0 >> 12;
    int s0 = m0 & 4095;
    int bh = b*4 + head;
    #pragma unroll
    for (int nt = 0; nt < 12; ++nt) {
        int ng = head*192 + nt*16 + li;
        float bias = bqkv[ng];
        int d = (nt & 3)*16 + li;
        if ((nt >> 2) == 2) {                         // V -> transposed [bh][d][s]
            ushort4 pk;
            pk.x = f2bf(acc[nt][0] + bias); pk.y = f2bf(acc[nt][1] + bias);
            pk.z = f2bf(acc[nt][2] + bias); pk.w = f2bf(acc[nt][3] + bias);
            *(ushort4*)&vT[(bh*64 + d)*4096 + s0 + g*4] = pk;
        } else if ((nt >> 2) == 0) {                  // Q (scale 0.125*log2e folded in)
            #pragma unroll
            for (int r = 0; r < 4; ++r)
                q[(bh*4096 + s0 + g*4 + r)*64 + d] = f2bf((acc[nt][r] + bias) * 0.1803368801f);
        } else {                                      // K
            #pragma unroll
            for (int r = 0; r < 4; ++r)
                kk[(bh*4096 + s0 + g*4 + r)*64 + d] = f2bf(acc[nt][r] + bias);
        }
    }
}

// ---------------- flash attention, 32x32x16 MFMA ----------------
// block = 4 waves (256 thr), Q-tile 128 (32 rows/wave), KV tiles of 64.
// K,V staged in LDS (global_load_lds w16, swizzled source, double-buffered, counted vmcnt).
// S^T = K x Q  -> softmax rows lane-local per column pair (lane, lane^32).
// P^T redistributed to the PV B-operand entirely in-register: cvt_pk_bf16 + permlane32_swap.
__global__ __launch_bounds__(256) void k_attn(
    const unsigned short* __restrict__ q, const unsigned short* __restrict__ kk,
    const unsigned short* __restrict__ vT, unsigned short* __restrict__ ao) {
    __shared__ __align__(16) unsigned short kbuf[2][4096];   // [64 j][64 d] swizzled
    __shared__ __align__(16) unsigned short vbuf[2][4096];   // [64 d][64 j] swizzled

    int qt = blockIdx.x, bh = blockIdx.y;
    int tid = threadIdx.x;
    int wid = tid >> 6, lane = tid & 63;
    int hi = lane >> 5, il = lane & 31;
    int swl = (il & 7) << 4;

    int qbase = qt * 128 + wid * 32;
    int qrow = bh * 4096 + qbase + il;
    short8 bq[4];                                 // Q B-frags: col=il, k=kc*16+hi*8..
    #pragma unroll
    for (int kc = 0; kc < 4; ++kc)
        bq[kc] = *(const short8*)&q[qrow*64 + kc*16 + hi*8];

    // staging: thread t covers LDS bytes [t*16,t*16+16) and [t*16+4096, +16) of each 8KB tile
    unsigned p16  = tid * 16;
    unsigned row0 = p16 >> 7;                     // 0..31 ; second load row = row0+32
    unsigned sw   = (row0 & 7) << 4;
    unsigned ks0  = p16 ^ sw;                     // K tile-local source byte
    unsigned vc0  = (p16 & 127u) ^ sw;            // V column byte within row
    const char* kbase = (const char*)kk + (size_t)bh * 524288;
    const char* vbas0 = (const char*)vT + (size_t)(bh*64 + row0) * 8192;
    const char* vbas1 = vbas0 + 32 * 8192;
    char* kd[2] = {(char*)kbuf[0] + wid*1024, (char*)kbuf[1] + wid*1024};
    char* vd[2] = {(char*)vbuf[0] + wid*1024, (char*)vbuf[1] + wid*1024};

    f32x16 o0 = fzero16(), o1 = fzero16();        // O^T: d-tiles 0/1, col i=il
    float m_run = -1e30f, l_run = 0.f;

    // prologue: stage tile 0 into buf 0
    gl_lds16(kbase + ks0, kd[0]);
    gl_lds16(kbase + 4096 + ks0, kd[0] + 4096);
    gl_lds16(vbas0 + vc0, vd[0]);
    gl_lds16(vbas1 + vc0, vd[0] + 4096);

    int cur = 0;
    for (int kt = 0; kt < 64; ++kt) {
        if (kt < 63) {                            // stage kt+1 into buf[cur^1]
            const char* kn = kbase + (size_t)(kt + 1) * 8192;
            size_t vo = (size_t)(kt + 1) * 128;
            char* kdn = kd[cur ^ 1]; char* vdn = vd[cur ^ 1];
            gl_lds16(kn + ks0, kdn);
            gl_lds16(kn + 4096 + ks0, kdn + 4096);
            gl_lds16(vbas0 + vo + vc0, vdn);
            gl_lds16(vbas1 + vo + vc0, vdn + 4096);
            asm volatile("s_waitcnt vmcnt(4)" ::: "memory");
        } else {
            asm volatile("s_waitcnt vmcnt(0)" ::: "memory");
        }
        __builtin_amdgcn_s_barrier();
        asm volatile("" ::: "memory");

        const char* kb = (const char*)kbuf[cur];
        const char* vb = (const char*)vbuf[cur];

        // S^T = K-tile x Q : two 32x32 j-tiles, K-dim 64 in 4 chunks
        f32x16 s0 = fzero16(), s1 = fzero16();
        #pragma unroll
        for (int kc = 0; kc < 4; ++kc) {
            int c = (kc*32 + hi*16) ^ swl;
            short8 ka0 = *(const short8*)(kb + il*128 + c);
            short8 ka1 = *(const short8*)(kb + 4096 + il*128 + c);
            s0 = __builtin_amdgcn_mfma_f32_32x32x16_bf16(ka0, bq[kc], s0, 0, 0, 0);
            s1 = __builtin_amdgcn_mfma_f32_32x32x16_bf16(ka1, bq[kc], s1, 0, 0, 0);
        }

        // online softmax (exp2 domain); column il's j-values split between lane and lane^32
        float mx = fmaxf(s0[0], s1[0]);
        #pragma unroll
        for (int r = 1; r < 16; ++r) mx = fmaxf(mx, fmaxf(s0[r], s1[r]));
        mx = fmaxf(mx, __shfl_xor(mx, 32));
        if (__any(mx > m_run)) {                  // deferred rescale
            float m_new = fmaxf(m_run, mx);
            float fac = fexp2(m_run - m_new);
            l_run *= fac;
            #pragma unroll
            for (int r = 0; r < 16; ++r) { o0[r] *= fac; o1[r] *= fac; }
            m_run = m_new;
        }
        float p0[16], p1[16];
        float ps = 0.f;
        #pragma unroll
        for (int r = 0; r < 16; ++r) {
            p0[r] = fexp2(s0[r] - m_run);
            p1[r] = fexp2(s1[r] - m_run);
            ps += p0[r] + p1[r];
        }
        ps += __shfl_xor(ps, 32);
        l_run += ps;

        // pack P -> bf16 pairs, permlane32_swap into PV B-frags (col=il, k-rows hi*8+0..7)
        unsigned w[16];
        #pragma unroll
        for (int t = 0; t < 2; ++t) {
            const float* pp = t ? p1 : p0;
            #pragma unroll
            for (int hh = 0; hh < 2; ++hh) {
                unsigned a = cvt_pk_bf16(pp[hh*8+0], pp[hh*8+1]);
                unsigned b = cvt_pk_bf16(pp[hh*8+2], pp[hh*8+3]);
                unsigned c = cvt_pk_bf16(pp[hh*8+4], pp[hh*8+5]);
                unsigned d = cvt_pk_bf16(pp[hh*8+6], pp[hh*8+7]);
                permswap(a, c);                   // -> [a_lo|c_lo], [a_hi|c_hi]
                permswap(b, d);
                int base = (t*2 + hh) * 4;
                w[base+0] = a; w[base+1] = b; w[base+2] = c; w[base+3] = d;
            }
        }

        // O^T += V^T x P^T : 4 j-chunks of 16, 2 d-tiles
        #pragma unroll
        for (int jc = 0; jc < 4; ++jc) {
            union { unsigned u[4]; short8 s8; } pb;
            pb.u[0] = w[jc*4+0]; pb.u[1] = w[jc*4+1];
            pb.u[2] = w[jc*4+2]; pb.u[3] = w[jc*4+3];
            int c = (jc*32 + hi*16) ^ swl;
            short8 va0 = *(const short8*)(vb + il*128 + c);
            short8 va1 = *(const short8*)(vb + 4096 + il*128 + c);
            o0 = __builtin_amdgcn_mfma_f32_32x32x16_bf16(va0, pb.s8, o0, 0, 0, 0);
            o1 = __builtin_amdgcn_mfma_f32_32x32x16_bf16(va1, pb.s8, o1, 0, 0, 0);
        }

        asm volatile("" ::: "memory");
        __builtin_amdgcn_s_barrier();
        cur ^= 1;
    }

    float inv = 1.f / l_run;
    int b = bh >> 2, hh = bh & 3;
    int s = qbase + il;
    unsigned short* aop = &ao[((size_t)(b*4096 + s))*256 + hh*64];
    #pragma unroll
    for (int rr = 0; rr < 4; ++rr) {              // d = dt*32 + rr*8 + hi*4 + 0..3
        ushort4 pk0, pk1;
        pk0.x = f2bf(o0[rr*4+0]*inv); pk0.y = f2bf(o0[rr*4+1]*inv);
        pk0.z = f2bf(o0[rr*4+2]*inv); pk0.w = f2bf(o0[rr*4+3]*inv);
        *(ushort4*)&aop[rr*8 + hi*4] = pk0;
        pk1.x = f2bf(o1[rr*4+0]*inv); pk1.y = f2bf(o1[rr*4+1]*inv);
        pk1.z = f2bf(o1[rr*4+2]*inv); pk1.w = f2bf(o1[rr*4+3]*inv);
        *(ushort4*)&aop[32 + rr*8 + hi*4] = pk1;
    }
}

// ---------------- out GEMM + bias + residual, transposed float4 store ----------------
__global__ __launch_bounds__(256) void k_out(
    const unsigned short* __restrict__ ao, const unsigned short* __restrict__ wT,
    const float* __restrict__ bout, const float* __restrict__ x,
    float* __restrict__ out) {
    int mt = blockIdx.x, ntb = blockIdx.y;
    int tid = threadIdx.x;
    int wid = tid >> 6, lane = tid & 63;
    int g = lane >> 4, li = lane & 15;
    int m0 = mt * 64 + wid * 16;
    int row = m0 + li;
    f32x4 acc[4];
    #pragma unroll
    for (int nt = 0; nt < 4; ++nt) acc[nt] = (f32x4){0.f,0.f,0.f,0.f};
    #pragma unroll
    for (int kt = 0; kt < 8; ++kt) {
        short8 a = *(const short8*)&ao[row*256 + kt*32 + g*8];
        #pragma unroll
        for (int nt = 0; nt < 4; ++nt) {
            int n = ntb*64 + nt*16 + li;
            short8 b = *(const short8*)&wT[n*256 + kt*32 + g*8];
            acc[nt] = __builtin_amdgcn_mfma_f32_16x16x32_bf16(a, b, acc[nt], 0, 0, 0);
        }
    }
    int b = m0 >> 12;
    int s0 = (m0 & 4095) + g*4;
    #pragma unroll
    for (int nt = 0; nt < 4; ++nt) {
        int c = ntb*64 + nt*16 + li;
        float bias = bout[c];
        int base = (b*256 + c)*4096 + s0;
        float4 xr = *(const float4*)&x[base];
        float4 ov;
        ov.x = acc[nt][0] + bias + xr.x;
        ov.y = acc[nt][1] + bias + xr.y;
        ov.z = acc[nt][2] + bias + xr.z;
        ov.w = acc[nt][3] + bias + xr.w;
        *(float4*)&out[base] = ov;
    }
}

extern "C" void kernel_launch(void* const* d_in, const int* in_sizes, int n_in,
                              void* d_out, int out_size, void* d_ws, size_t ws_size,
                              hipStream_t stream) {
    (void)in_sizes; (void)n_in; (void)out_size; (void)ws_size;
    const float* x     = (const float*)d_in[0];
    const float* gamma = (const float*)d_in[1];
    const float* beta  = (const float*)d_in[2];
    const float* wqkv  = (const float*)d_in[3];
    const float* bqkv  = (const float*)d_in[4];
    const float* wout  = (const float*)d_in[5];
    const float* bout  = (const float*)d_in[6];
    float* out = (float*)d_out;

    char* ws = (char*)d_ws;
    unsigned short* h     = (unsigned short*)(ws);                    // 8 MB  [B*S][256] bf16
    unsigned short* q     = (unsigned short*)(ws + (8u<<20));         // 8 MB  [bh][S][64]
    unsigned short* kk    = (unsigned short*)(ws + (16u<<20));        // 8 MB  [bh][S][64]
    unsigned short* vT    = (unsigned short*)(ws + (24u<<20));        // 8 MB  [bh][64][S]
    unsigned short* ao    = (unsigned short*)(ws + (32u<<20));        // 8 MB  [B*S][256]
    unsigned short* wqkvT = (unsigned short*)(ws + (40u<<20));        // 384 KB [768][256]
    unsigned short* woutT = (unsigned short*)(ws + (40u<<20) + 393216);// 128 KB [256][256]
    float*          stats = (float*)(ws + (40u<<20) + 524288);        // 1 KB

    k_gn_stats<<<128, 1024, 0, stream>>>(x, stats);
    k_cvt_w<<<768, 256, 0, stream>>>(wqkv, wout, wqkvT, woutT);
    k_gn_norm<<<dim3(64, 4, 4), 256, 0, stream>>>(x, gamma, beta, stats, h);
    k_qkv<<<dim3(256, 4), 256, 0, stream>>>(h, wqkvT, bqkv, q, kk, vT);
    k_attn<<<dim3(32, 16), 256, 0, stream>>>(q, kk, vT, ao);
    k_out<<<dim3(256, 4), 256, 0, stream>>>(ao, woutT, bout, x, out);
}

// Round 5
// 187.235 us; speedup vs baseline: 1.0962x; 1.0962x over previous
//
#include <hip/hip_runtime.h>
#include <hip/hip_bf16.h>

// AttentionBlock: GroupNorm -> QKV -> 4-head attention (S=4096, D=64) -> out proj -> +residual
// B=4, C=256, H=W=64, S=4096, N_GROUPS=32, N_HEADS=4, D_K=64

typedef __attribute__((ext_vector_type(8))) short short8;   // 8 bf16 (4 VGPRs) MFMA A/B frag
typedef __attribute__((ext_vector_type(4))) float f32x4;    // 16x16 MFMA C/D frag
typedef __attribute__((ext_vector_type(16))) float f32x16;  // 32x32 MFMA C/D frag

__device__ __forceinline__ unsigned short f2bf(float f) {
    union { float f; unsigned u; } v; v.f = f;
    unsigned r = v.u + 0x7FFF + ((v.u >> 16) & 1);
    return (unsigned short)(r >> 16);
}

__device__ __forceinline__ unsigned cvt_pk_bf16(float lo, float hi) {
    unsigned r;
    asm("v_cvt_pk_bf16_f32 %0, %1, %2" : "=v"(r) : "v"(lo), "v"(hi));
    return r;
}

__device__ __forceinline__ void permswap(unsigned &x, unsigned &y) {
    // x' = [x_lo | y_lo], y' = [x_hi | y_hi]   (vdst hi-half <-> vsrc lo-half)
    asm("v_permlane32_swap_b32 %0, %1" : "+v"(x), "+v"(y));
}

__device__ __forceinline__ float fexp2(float x) {   // D = 2^S0
    float r;
    asm("v_exp_f32 %0, %1" : "=v"(r) : "v"(x));
    return r;
}

__device__ __forceinline__ void gl_lds16(const void* g, void* l) {
    __builtin_amdgcn_global_load_lds(
        (const __attribute__((address_space(1))) void*)(g),
        (__attribute__((address_space(3))) void*)(l), 16, 0, 0);
}

__device__ __forceinline__ f32x16 fzero16() {
    f32x16 z;
    #pragma unroll
    for (int i = 0; i < 16; ++i) z[i] = 0.f;
    return z;
}

// ---------------- GroupNorm stats: one block per (b,g), 8ch*4096 = 32768 elems ----------------
__global__ __launch_bounds__(1024) void k_gn_stats(const float* __restrict__ x,
                                                   float* __restrict__ stats) {
    int bg = blockIdx.x;                       // b*32+g ; group channels contiguous
    const float4* xp = (const float4*)(x + bg * 32768);
    float s1 = 0.f, s2 = 0.f;
    for (int i = threadIdx.x; i < 8192; i += 1024) {
        float4 v = xp[i];
        s1 += v.x + v.y + v.z + v.w;
        s2 += v.x*v.x + v.y*v.y + v.z*v.z + v.w*v.w;
    }
    #pragma unroll
    for (int off = 32; off; off >>= 1) {
        s1 += __shfl_down(s1, off);
        s2 += __shfl_down(s2, off);
    }
    __shared__ float r1[16], r2[16];
    int wid = threadIdx.x >> 6;
    if ((threadIdx.x & 63) == 0) { r1[wid] = s1; r2[wid] = s2; }
    __syncthreads();
    if (threadIdx.x == 0) {
        float a = 0.f, b = 0.f;
        #pragma unroll
        for (int i = 0; i < 16; ++i) { a += r1[i]; b += r2[i]; }
        float mean = a * (1.f/32768.f);
        float var  = b * (1.f/32768.f) - mean*mean;
        stats[bg*2]   = mean;
        stats[bg*2+1] = rsqrtf(var + 1e-5f);
    }
}

// ------------- convert + transpose weights to bf16 [N][K] so B-frags are contiguous -------------
__global__ void k_cvt_w(const float* __restrict__ wqkv, const float* __restrict__ wout,
                        unsigned short* __restrict__ wqkvT, unsigned short* __restrict__ woutT) {
    int i = blockIdx.x * 256 + threadIdx.x;
    if (i < 196608) {                       // w_qkv [256][768] -> [768][256]
        int k = i / 768, n = i - k * 768;
        wqkvT[n*256 + k] = f2bf(wqkv[i]);
    }
    if (i < 65536) {                        // w_out [256][256] -> [256][256]^T
        int k = i >> 8, n = i & 255;
        woutT[n*256 + k] = f2bf(wout[i]);
    }
}

// ------- normalize + transpose: x[b][c][s] fp32 -> h[b][s][c] bf16 via 64x64 LDS tile -------
__global__ __launch_bounds__(256) void k_gn_norm(
    const float* __restrict__ x, const float* __restrict__ gamma,
    const float* __restrict__ beta, const float* __restrict__ stats,
    unsigned short* __restrict__ h) {
    __shared__ unsigned short t[64][72];          // pad 8 -> decent bank spread
    int s0 = blockIdx.x * 64, c0 = blockIdx.y * 64, b = blockIdx.z;
    int tid = threadIdx.x;
    int sl = (tid & 15) * 4;                      // float4 along s
    int cr = tid >> 4;
    #pragma unroll
    for (int p = 0; p < 4; ++p) {
        int c = c0 + cr + p * 16;
        float4 v = *(const float4*)&x[(b*256 + c)*4096 + s0 + sl];
        int sg = (b*32 + (c >> 3)) * 2;
        float mean = stats[sg], rstd = stats[sg+1];
        float sa = rstd * gamma[c];
        float sb = beta[c] - mean * sa;
        ushort4 pk;
        pk.x = f2bf(v.x*sa + sb); pk.y = f2bf(v.y*sa + sb);
        pk.z = f2bf(v.z*sa + sb); pk.w = f2bf(v.w*sa + sb);
        *(ushort4*)&t[cr + p*16][sl] = pk;
    }
    __syncthreads();
    int sr = tid >> 2;                            // 0..63 (s row)
    int cc = (tid & 3) * 16;                      // 16 channels per thread
    unsigned rr[8];
    #pragma unroll
    for (int j = 0; j < 8; ++j)
        rr[j] = (unsigned)t[cc + 2*j][sr] | ((unsigned)t[cc + 2*j + 1][sr] << 16);
    unsigned short* hp = &h[(b*4096 + s0 + sr)*256 + c0];
    *(uint4*)&hp[cc]     = make_uint4(rr[0], rr[1], rr[2], rr[3]);
    *(uint4*)&hp[cc + 8] = make_uint4(rr[4], rr[5], rr[6], rr[7]);
}

// ---------------- QKV GEMM: h[16384][256] @ wqkvT -> q,k [bh][S][64], vT [bh][64][S] ----------------
// Q gets 0.125 * log2(e) folded in (attention softmax runs in exp2 domain).
__global__ __launch_bounds__(256) void k_qkv(
    const unsigned short* __restrict__ h, const unsigned short* __restrict__ wT,
    const float* __restrict__ bqkv,
    unsigned short* __restrict__ q, unsigned short* __restrict__ kk,
    unsigned short* __restrict__ vT) {
    int mt = blockIdx.x, head = blockIdx.y;
    int tid = threadIdx.x;
    int wid = tid >> 6, lane = tid & 63;
    int g = lane >> 4, li = lane & 15;
    int m0 = mt * 64 + wid * 16;
    int row = m0 + li;
    f32x4 acc[12];
    #pragma unroll
    for (int nt = 0; nt < 12; ++nt) acc[nt] = (f32x4){0.f,0.f,0.f,0.f};
    #pragma unroll
    for (int kt = 0; kt < 8; ++kt) {
        short8 a = *(const short8*)&h[row*256 + kt*32 + g*8];
        #pragma unroll
        for (int nt = 0; nt < 12; ++nt) {
            int n = head*192 + nt*16 + li;
            short8 b = *(const short8*)&wT[n*256 + kt*32 + g*8];
            acc[nt] = __builtin_amdgcn_mfma_f32_16x16x32_bf16(a, b, acc[nt], 0, 0, 0);
        }
    }
    int b = m0 >> 12;
    int s0 = m0 & 4095;
    int bh = b*4 + head;
    #pragma unroll
    for (int nt = 0; nt < 12; ++nt) {
        int ng = head*192 + nt*16 + li;
        float bias = bqkv[ng];
        int d = (nt & 3)*16 + li;
        if ((nt >> 2) == 2) {                         // V -> transposed [bh][d][s]
            ushort4 pk;
            pk.x = f2bf(acc[nt][0] + bias); pk.y = f2bf(acc[nt][1] + bias);
            pk.z = f2bf(acc[nt][2] + bias); pk.w = f2bf(acc[nt][3] + bias);
            *(ushort4*)&vT[(bh*64 + d)*4096 + s0 + g*4] = pk;
        } else if ((nt >> 2) == 0) {                  // Q (scale 0.125*log2e folded in)
            #pragma unroll
            for (int r = 0; r < 4; ++r)
                q[(bh*4096 + s0 + g*4 + r)*64 + d] = f2bf((acc[nt][r] + bias) * 0.1803368801f);
        } else {                                      // K
            #pragma unroll
            for (int r = 0; r < 4; ++r)
                kk[(bh*4096 + s0 + g*4 + r)*64 + d] = f2bf(acc[nt][r] + bias);
        }
    }
}

// ---------------- flash attention, 32x32x16 MFMA, KV-stream split, deferred online max -----------
// block = 8 waves (512 thr). Wave (qw, st): qw = Q-subtile (32 rows), st = KV stream (even/odd tiles).
// Each stream keeps its own (m, l, O); exact flash combine at the end via LDS.
__global__ __launch_bounds__(512, 4) void k_attn(
    const unsigned short* __restrict__ q, const unsigned short* __restrict__ kk,
    const unsigned short* __restrict__ vT, unsigned short* __restrict__ ao) {
    __shared__ __align__(16) char smem[65536];    // [dbuf][stream] K 8KB x4 | V 8KB x4

    int qt = blockIdx.x, bh = blockIdx.y;
    int tid = threadIdx.x;
    int wid = tid >> 6, lane = tid & 63;
    int qw = wid & 3, st = wid >> 2;
    int hi = lane >> 5, il = lane & 31;
    int swl = (il & 7) << 4;

    int qbase = qt * 128 + qw * 32;
    int qrow = bh * 4096 + qbase + il;
    short8 bq[4];                                 // Q B-frags: col=il, k=kc*16+hi*8..
    #pragma unroll
    for (int kc = 0; kc < 4; ++kc)
        bq[kc] = *(const short8*)&q[qrow*64 + kc*16 + hi*8];

    // staging geometry: 512 threads cover one 8KB tile (16B each)
    unsigned p16  = tid * 16;
    unsigned row0 = p16 >> 7;                     // 0..63
    unsigned sw   = (row0 & 7) << 4;
    unsigned ks0  = p16 ^ sw;                     // K tile-local swizzled source byte
    unsigned vc0  = (p16 & 127u) ^ sw;            // V column byte within row
    const char* kbase = (const char*)kk + (size_t)bh * 524288;
    const char* vbase = (const char*)vT + (size_t)(bh*64 + row0) * 8192;
    unsigned woff = wid * 1024;

#define STAGE_PAIR(d, pair) do {                                             \
    const char* _k0 = kbase + (size_t)(2*(pair)) * 8192;                     \
    size_t _vo = (size_t)(2*(pair)) * 128;                                   \
    gl_lds16(_k0 + ks0,              smem + ((d)*2+0)*8192 + woff);          \
    gl_lds16(_k0 + 8192 + ks0,       smem + ((d)*2+1)*8192 + woff);          \
    gl_lds16(vbase + _vo + vc0,       smem + 32768 + ((d)*2+0)*8192 + woff); \
    gl_lds16(vbase + _vo + 128 + vc0, smem + 32768 + ((d)*2+1)*8192 + woff); \
} while (0)

    f32x16 o0 = fzero16(), o1 = fzero16();        // O^T: d-tiles 0/1, col i=il
    float m_run = -1e30f, l_loc = 0.f;

    STAGE_PAIR(0, 0);
    int cur = 0;
    for (int tp = 0; tp < 32; ++tp) {
        if (tp < 31) {
            STAGE_PAIR(cur ^ 1, tp + 1);
            asm volatile("s_waitcnt vmcnt(4)" ::: "memory");
        } else {
            asm volatile("s_waitcnt vmcnt(0)" ::: "memory");
        }
        __builtin_amdgcn_s_barrier();
        asm volatile("" ::: "memory");

        const char* kb = smem + (cur*2 + st) * 8192;
        const char* vb = smem + 32768 + (cur*2 + st) * 8192;

        // S^T = K-tile x Q : two 32x32 j-tiles, K-dim 64 in 4 chunks
        f32x16 s0 = fzero16(), s1 = fzero16();
        __builtin_amdgcn_s_setprio(1);
        #pragma unroll
        for (int kc = 0; kc < 4; ++kc) {
            int c = (kc*32 + hi*16) ^ swl;
            short8 ka0 = *(const short8*)(kb + il*128 + c);
            short8 ka1 = *(const short8*)(kb + 4096 + il*128 + c);
            s0 = __builtin_amdgcn_mfma_f32_32x32x16_bf16(ka0, bq[kc], s0, 0, 0, 0);
            s1 = __builtin_amdgcn_mfma_f32_32x32x16_bf16(ka1, bq[kc], s1, 0, 0, 0);
        }
        __builtin_amdgcn_s_setprio(0);

        // online softmax (exp2 domain); row il's j-values split between lane and lane^32
        float mx = fmaxf(s0[0], s1[0]);
        #pragma unroll
        for (int r = 1; r < 16; ++r) mx = fmaxf(mx, fmaxf(s0[r], s1[r]));
        mx = fmaxf(mx, __shfl_xor(mx, 32));
        if (__any(mx > m_run)) {                  // deferred rescale
            float m_new = fmaxf(m_run, mx);
            float fac = fexp2(m_run - m_new);
            l_loc *= fac;
            #pragma unroll
            for (int r = 0; r < 16; ++r) { o0[r] *= fac; o1[r] *= fac; }
            m_run = m_new;
        }
        float p0[16], p1[16];
        #pragma unroll
        for (int r = 0; r < 16; ++r) {
            p0[r] = fexp2(s0[r] - m_run);
            p1[r] = fexp2(s1[r] - m_run);
            l_loc += p0[r] + p1[r];
        }

        // pack P -> bf16 pairs, permlane32_swap into PV B-frags (col=il, k-rows hi*8+0..7)
        unsigned w[16];
        #pragma unroll
        for (int t = 0; t < 2; ++t) {
            const float* pp = t ? p1 : p0;
            #pragma unroll
            for (int hh = 0; hh < 2; ++hh) {
                unsigned a = cvt_pk_bf16(pp[hh*8+0], pp[hh*8+1]);
                unsigned b = cvt_pk_bf16(pp[hh*8+2], pp[hh*8+3]);
                unsigned c = cvt_pk_bf16(pp[hh*8+4], pp[hh*8+5]);
                unsigned d = cvt_pk_bf16(pp[hh*8+6], pp[hh*8+7]);
                permswap(a, c);                   // -> [a_lo|c_lo], [a_hi|c_hi]
                permswap(b, d);
                int base = (t*2 + hh) * 4;
                w[base+0] = a; w[base+1] = b; w[base+2] = c; w[base+3] = d;
            }
        }

        // O^T += V^T x P^T : 4 j-chunks of 16, 2 d-tiles
        __builtin_amdgcn_s_setprio(1);
        #pragma unroll
        for (int jc = 0; jc < 4; ++jc) {
            union { unsigned u[4]; short8 s8; } pb;
            pb.u[0] = w[jc*4+0]; pb.u[1] = w[jc*4+1];
            pb.u[2] = w[jc*4+2]; pb.u[3] = w[jc*4+3];
            int c = (jc*32 + hi*16) ^ swl;
            short8 va0 = *(const short8*)(vb + il*128 + c);
            short8 va1 = *(const short8*)(vb + 4096 + il*128 + c);
            o0 = __builtin_amdgcn_mfma_f32_32x32x16_bf16(va0, pb.s8, o0, 0, 0, 0);
            o1 = __builtin_amdgcn_mfma_f32_32x32x16_bf16(va1, pb.s8, o1, 0, 0, 0);
        }
        __builtin_amdgcn_s_setprio(0);

        asm volatile("" ::: "memory");
        __builtin_amdgcn_s_barrier();
        cur ^= 1;
    }
#undef STAGE_PAIR

    l_loc += __shfl_xor(l_loc, 32);

    // combine the two KV streams (each with its own max): st=1 writes, st=0 merges + outputs
    float* red = (float*)smem;                    // 256 slots x 34 floats = 34 KB (dead K/V region)
    int slot = ((qw*64 + lane) * 34);
    if (st == 1) {
        #pragma unroll
        for (int r = 0; r < 16; ++r) { red[slot + r] = o0[r]; red[slot + 16 + r] = o1[r]; }
        red[slot + 32] = l_loc;
        red[slot + 33] = m_run;
    }
    __syncthreads();
    if (st == 0) {
        float m1 = red[slot + 33], l1 = red[slot + 32];
        float m = fmaxf(m_run, m1);
        float f0 = fexp2(m_run - m), f1 = fexp2(m1 - m);
        float inv = 1.f / (l_loc * f0 + l1 * f1);
        float a0 = f0 * inv, a1 = f1 * inv;
        int b = bh >> 2, hh = bh & 3;
        int s = qbase + il;
        unsigned short* aop = &ao[((size_t)(b*4096 + s))*256 + hh*64];
        #pragma unroll
        for (int rr = 0; rr < 4; ++rr) {          // d = dt*32 + rr*8 + hi*4 + 0..3
            ushort4 pk0, pk1;
            pk0.x = f2bf(o0[rr*4+0]*a0 + red[slot + rr*4+0]*a1);
            pk0.y = f2bf(o0[rr*4+1]*a0 + red[slot + rr*4+1]*a1);
            pk0.z = f2bf(o0[rr*4+2]*a0 + red[slot + rr*4+2]*a1);
            pk0.w = f2bf(o0[rr*4+3]*a0 + red[slot + rr*4+3]*a1);
            *(ushort4*)&aop[rr*8 + hi*4] = pk0;
            pk1.x = f2bf(o1[rr*4+0]*a0 + red[slot + 16 + rr*4+0]*a1);
            pk1.y = f2bf(o1[rr*4+1]*a0 + red[slot + 16 + rr*4+1]*a1);
            pk1.z = f2bf(o1[rr*4+2]*a0 + red[slot + 16 + rr*4+2]*a1);
            pk1.w = f2bf(o1[rr*4+3]*a0 + red[slot + 16 + rr*4+3]*a1);
            *(ushort4*)&aop[32 + rr*8 + hi*4] = pk1;
        }
    }
}

// ---------------- out GEMM + bias + residual, transposed float4 store ----------------
__global__ __launch_bounds__(256) void k_out(
    const unsigned short* __restrict__ ao, const unsigned short* __restrict__ wT,
    const float* __restrict__ bout, const float* __restrict__ x,
    float* __restrict__ out) {
    int mt = blockIdx.x, ntb = blockIdx.y;
    int tid = threadIdx.x;
    int wid = tid >> 6, lane = tid & 63;
    int g = lane >> 4, li = lane & 15;
    int m0 = mt * 64 + wid * 16;
    int row = m0 + li;
    f32x4 acc[4];
    #pragma unroll
    for (int nt = 0; nt < 4; ++nt) acc[nt] = (f32x4){0.f,0.f,0.f,0.f};
    #pragma unroll
    for (int kt = 0; kt < 8; ++kt) {
        short8 a = *(const short8*)&ao[row*256 + kt*32 + g*8];
        #pragma unroll
        for (int nt = 0; nt < 4; ++nt) {
            int n = ntb*64 + nt*16 + li;
            short8 b = *(const short8*)&wT[n*256 + kt*32 + g*8];
            acc[nt] = __builtin_amdgcn_mfma_f32_16x16x32_bf16(a, b, acc[nt], 0, 0, 0);
        }
    }
    int b = m0 >> 12;
    int s0 = (m0 & 4095) + g*4;
    #pragma unroll
    for (int nt = 0; nt < 4; ++nt) {
        int c = ntb*64 + nt*16 + li;
        float bias = bout[c];
        int base = (b*256 + c)*4096 + s0;
        float4 xr = *(const float4*)&x[base];
        float4 ov;
        ov.x = acc[nt][0] + bias + xr.x;
        ov.y = acc[nt][1] + bias + xr.y;
        ov.z = acc[nt][2] + bias + xr.z;
        ov.w = acc[nt][3] + bias + xr.w;
        *(float4*)&out[base] = ov;
    }
}

extern "C" void kernel_launch(void* const* d_in, const int* in_sizes, int n_in,
                              void* d_out, int out_size, void* d_ws, size_t ws_size,
                              hipStream_t stream) {
    (void)in_sizes; (void)n_in; (void)out_size; (void)ws_size;
    const float* x     = (const float*)d_in[0];
    const float* gamma = (const float*)d_in[1];
    const float* beta  = (const float*)d_in[2];
    const float* wqkv  = (const float*)d_in[3];
    const float* bqkv  = (const float*)d_in[4];
    const float* wout  = (const float*)d_in[5];
    const float* bout  = (const float*)d_in[6];
    float* out = (float*)d_out;

    char* ws = (char*)d_ws;
    unsigned short* h     = (unsigned short*)(ws);                    // 8 MB  [B*S][256] bf16
    unsigned short* q     = (unsigned short*)(ws + (8u<<20));         // 8 MB  [bh][S][64]
    unsigned short* kk    = (unsigned short*)(ws + (16u<<20));        // 8 MB  [bh][S][64]
    unsigned short* vT    = (unsigned short*)(ws + (24u<<20));        // 8 MB  [bh][64][S]
    unsigned short* ao    = (unsigned short*)(ws + (32u<<20));        // 8 MB  [B*S][256]
    unsigned short* wqkvT = (unsigned short*)(ws + (40u<<20));        // 384 KB [768][256]
    unsigned short* woutT = (unsigned short*)(ws + (40u<<20) + 393216);// 128 KB [256][256]
    float*          stats = (float*)(ws + (40u<<20) + 524288);        // 1 KB

    k_gn_stats<<<128, 1024, 0, stream>>>(x, stats);
    k_cvt_w<<<768, 256, 0, stream>>>(wqkv, wout, wqkvT, woutT);
    k_gn_norm<<<dim3(64, 4, 4), 256, 0, stream>>>(x, gamma, beta, stats, h);
    k_qkv<<<dim3(256, 4), 256, 0, stream>>>(h, wqkvT, bqkv, q, kk, vT);
    k_attn<<<dim3(32, 16), 512, 0, stream>>>(q, kk, vT, ao);
    k_out<<<dim3(256, 4), 256, 0, stream>>>(ao, woutT, bout, x, out);
}

// Round 6
// 180.538 us; speedup vs baseline: 1.1369x; 1.0371x over previous
//
#include <hip/hip_runtime.h>
#include <hip/hip_bf16.h>

// AttentionBlock: GroupNorm -> QKV -> 4-head attention (S=4096, D=64) -> out proj -> +residual
// B=4, C=256, H=W=64, S=4096, N_GROUPS=32, N_HEADS=4, D_K=64

typedef __attribute__((ext_vector_type(8))) short short8;   // 8 bf16 (4 VGPRs) MFMA A/B frag
typedef __attribute__((ext_vector_type(4))) float f32x4;    // 16x16 MFMA C/D frag
typedef __attribute__((ext_vector_type(16))) float f32x16;  // 32x32 MFMA C/D frag

__device__ __forceinline__ unsigned short f2bf(float f) {
    union { float f; unsigned u; } v; v.f = f;
    unsigned r = v.u + 0x7FFF + ((v.u >> 16) & 1);
    return (unsigned short)(r >> 16);
}

__device__ __forceinline__ unsigned cvt_pk_bf16(float lo, float hi) {
    unsigned r;
    asm("v_cvt_pk_bf16_f32 %0, %1, %2" : "=v"(r) : "v"(lo), "v"(hi));
    return r;
}

__device__ __forceinline__ void permswap(unsigned &x, unsigned &y) {
    // x' = [x_lo | y_lo], y' = [x_hi | y_hi]   (vdst hi-half <-> vsrc lo-half)
    asm("v_permlane32_swap_b32 %0, %1" : "+v"(x), "+v"(y));
}

__device__ __forceinline__ float fexp2(float x) {   // D = 2^S0
    float r;
    asm("v_exp_f32 %0, %1" : "=v"(r) : "v"(x));
    return r;
}

__device__ __forceinline__ void gl_lds16(const void* g, void* l) {
    __builtin_amdgcn_global_load_lds(
        (const __attribute__((address_space(1))) void*)(g),
        (__attribute__((address_space(3))) void*)(l), 16, 0, 0);
}

__device__ __forceinline__ f32x16 fzero16() {
    f32x16 z;
    #pragma unroll
    for (int i = 0; i < 16; ++i) z[i] = 0.f;
    return z;
}

// ---------------- GroupNorm stats: one block per (b,g), 8ch*4096 = 32768 elems ----------------
__global__ __launch_bounds__(1024) void k_gn_stats(const float* __restrict__ x,
                                                   float* __restrict__ stats) {
    int bg = blockIdx.x;                       // b*32+g ; group channels contiguous
    const float4* xp = (const float4*)(x + bg * 32768);
    float s1 = 0.f, s2 = 0.f;
    for (int i = threadIdx.x; i < 8192; i += 1024) {
        float4 v = xp[i];
        s1 += v.x + v.y + v.z + v.w;
        s2 += v.x*v.x + v.y*v.y + v.z*v.z + v.w*v.w;
    }
    #pragma unroll
    for (int off = 32; off; off >>= 1) {
        s1 += __shfl_down(s1, off);
        s2 += __shfl_down(s2, off);
    }
    __shared__ float r1[16], r2[16];
    int wid = threadIdx.x >> 6;
    if ((threadIdx.x & 63) == 0) { r1[wid] = s1; r2[wid] = s2; }
    __syncthreads();
    if (threadIdx.x == 0) {
        float a = 0.f, b = 0.f;
        #pragma unroll
        for (int i = 0; i < 16; ++i) { a += r1[i]; b += r2[i]; }
        float mean = a * (1.f/32768.f);
        float var  = b * (1.f/32768.f) - mean*mean;
        stats[bg*2]   = mean;
        stats[bg*2+1] = rsqrtf(var + 1e-5f);
    }
}

// ------------- convert + transpose weights to bf16 [N][K] so B-frags are contiguous -------------
__global__ void k_cvt_w(const float* __restrict__ wqkv, const float* __restrict__ wout,
                        unsigned short* __restrict__ wqkvT, unsigned short* __restrict__ woutT) {
    int i = blockIdx.x * 256 + threadIdx.x;
    if (i < 196608) {                       // w_qkv [256][768] -> [768][256]
        int k = i / 768, n = i - k * 768;
        wqkvT[n*256 + k] = f2bf(wqkv[i]);
    }
    if (i < 65536) {                        // w_out [256][256] -> [256][256]^T
        int k = i >> 8, n = i & 255;
        woutT[n*256 + k] = f2bf(wout[i]);
    }
}

// ------- normalize + transpose: x[b][c][s] fp32 -> h[b][s][c] bf16 via 64x64 LDS tile -------
__global__ __launch_bounds__(256) void k_gn_norm(
    const float* __restrict__ x, const float* __restrict__ gamma,
    const float* __restrict__ beta, const float* __restrict__ stats,
    unsigned short* __restrict__ h) {
    __shared__ unsigned short t[64][72];          // pad 8 -> decent bank spread
    int s0 = blockIdx.x * 64, c0 = blockIdx.y * 64, b = blockIdx.z;
    int tid = threadIdx.x;
    int sl = (tid & 15) * 4;                      // float4 along s
    int cr = tid >> 4;
    #pragma unroll
    for (int p = 0; p < 4; ++p) {
        int c = c0 + cr + p * 16;
        float4 v = *(const float4*)&x[(b*256 + c)*4096 + s0 + sl];
        int sg = (b*32 + (c >> 3)) * 2;
        float mean = stats[sg], rstd = stats[sg+1];
        float sa = rstd * gamma[c];
        float sb = beta[c] - mean * sa;
        ushort4 pk;
        pk.x = f2bf(v.x*sa + sb); pk.y = f2bf(v.y*sa + sb);
        pk.z = f2bf(v.z*sa + sb); pk.w = f2bf(v.w*sa + sb);
        *(ushort4*)&t[cr + p*16][sl] = pk;
    }
    __syncthreads();
    int sr = tid >> 2;                            // 0..63 (s row)
    int cc = (tid & 3) * 16;                      // 16 channels per thread
    unsigned rr[8];
    #pragma unroll
    for (int j = 0; j < 8; ++j)
        rr[j] = (unsigned)t[cc + 2*j][sr] | ((unsigned)t[cc + 2*j + 1][sr] << 16);
    unsigned short* hp = &h[(b*4096 + s0 + sr)*256 + c0];
    *(uint4*)&hp[cc]     = make_uint4(rr[0], rr[1], rr[2], rr[3]);
    *(uint4*)&hp[cc + 8] = make_uint4(rr[4], rr[5], rr[6], rr[7]);
}

// ---------------- QKV GEMM: h[16384][256] @ wqkvT -> q,k [bh][S][64], vT [bh][64][S] ----------------
// Q gets 0.125 * log2(e) folded in (attention softmax runs in exp2 domain).
__global__ __launch_bounds__(256) void k_qkv(
    const unsigned short* __restrict__ h, const unsigned short* __restrict__ wT,
    const float* __restrict__ bqkv,
    unsigned short* __restrict__ q, unsigned short* __restrict__ kk,
    unsigned short* __restrict__ vT) {
    int mt = blockIdx.x, head = blockIdx.y;
    int tid = threadIdx.x;
    int wid = tid >> 6, lane = tid & 63;
    int g = lane >> 4, li = lane & 15;
    int m0 = mt * 64 + wid * 16;
    int row = m0 + li;
    f32x4 acc[12];
    #pragma unroll
    for (int nt = 0; nt < 12; ++nt) acc[nt] = (f32x4){0.f,0.f,0.f,0.f};
    #pragma unroll
    for (int kt = 0; kt < 8; ++kt) {
        short8 a = *(const short8*)&h[row*256 + kt*32 + g*8];
        #pragma unroll
        for (int nt = 0; nt < 12; ++nt) {
            int n = head*192 + nt*16 + li;
            short8 b = *(const short8*)&wT[n*256 + kt*32 + g*8];
            acc[nt] = __builtin_amdgcn_mfma_f32_16x16x32_bf16(a, b, acc[nt], 0, 0, 0);
        }
    }
    int b = m0 >> 12;
    int s0 = m0 & 4095;
    int bh = b*4 + head;
    #pragma unroll
    for (int nt = 0; nt < 12; ++nt) {
        int ng = head*192 + nt*16 + li;
        float bias = bqkv[ng];
        int d = (nt & 3)*16 + li;
        if ((nt >> 2) == 2) {                         // V -> transposed [bh][d][s]
            ushort4 pk;
            pk.x = f2bf(acc[nt][0] + bias); pk.y = f2bf(acc[nt][1] + bias);
            pk.z = f2bf(acc[nt][2] + bias); pk.w = f2bf(acc[nt][3] + bias);
            *(ushort4*)&vT[(bh*64 + d)*4096 + s0 + g*4] = pk;
        } else if ((nt >> 2) == 0) {                  // Q (scale 0.125*log2e folded in)
            #pragma unroll
            for (int r = 0; r < 4; ++r)
                q[(bh*4096 + s0 + g*4 + r)*64 + d] = f2bf((acc[nt][r] + bias) * 0.1803368801f);
        } else {                                      // K
            #pragma unroll
            for (int r = 0; r < 4; ++r)
                kk[(bh*4096 + s0 + g*4 + r)*64 + d] = f2bf(acc[nt][r] + bias);
        }
    }
}

// ---------------- flash attention, 32x32x16 MFMA, KV-stream split, deferred online max -----------
// block = 8 waves (512 thr). Wave (qw, st): qw = Q-subtile (32 rows), st = KV stream (even/odd tiles).
// XCD-aware block remap: bh-pair per XCD so K+V (4MB) is L2-resident.
// Single barrier per tile: STAGE(next) -> compute(cur) -> vmcnt(0) -> barrier.
__global__ __launch_bounds__(512, 4) void k_attn(
    const unsigned short* __restrict__ q, const unsigned short* __restrict__ kk,
    const unsigned short* __restrict__ vT, unsigned short* __restrict__ ao) {
    __shared__ __align__(16) char smem[65536];    // [dbuf][stream] K 8KB x4 | V 8KB x4

    int n = blockIdx.x;                           // 512 blocks; XCD = n & 7 (round-robin dispatch)
    int qt = n >> 4;
    int bh = ((n & 7) << 1) | ((n >> 3) & 1);     // 2 heads per XCD -> K/V fits 4MB L2
    int tid = threadIdx.x;
    int wid = tid >> 6, lane = tid & 63;
    int qw = wid & 3, st = wid >> 2;
    int hi = lane >> 5, il = lane & 31;
    int swl = (il & 7) << 4;

    int qbase = qt * 128 + qw * 32;
    int qrow = bh * 4096 + qbase + il;
    short8 bq[4];                                 // Q B-frags: col=il, k=kc*16+hi*8..
    #pragma unroll
    for (int kc = 0; kc < 4; ++kc)
        bq[kc] = *(const short8*)&q[qrow*64 + kc*16 + hi*8];

    // staging geometry: 512 threads cover one 8KB tile (16B each)
    unsigned p16  = tid * 16;
    unsigned row0 = p16 >> 7;                     // 0..63
    unsigned sw   = (row0 & 7) << 4;
    unsigned ks0  = p16 ^ sw;                     // K tile-local swizzled source byte
    unsigned vc0  = (p16 & 127u) ^ sw;            // V column byte within row
    const char* kbase = (const char*)kk + (size_t)bh * 524288;
    const char* vbase = (const char*)vT + (size_t)(bh*64 + row0) * 8192;
    unsigned woff = wid * 1024;

#define STAGE_PAIR(d, pair) do {                                             \
    const char* _k0 = kbase + (size_t)(2*(pair)) * 8192;                     \
    size_t _vo = (size_t)(2*(pair)) * 128;                                   \
    gl_lds16(_k0 + ks0,              smem + ((d)*2+0)*8192 + woff);          \
    gl_lds16(_k0 + 8192 + ks0,       smem + ((d)*2+1)*8192 + woff);          \
    gl_lds16(vbase + _vo + vc0,       smem + 32768 + ((d)*2+0)*8192 + woff); \
    gl_lds16(vbase + _vo + 128 + vc0, smem + 32768 + ((d)*2+1)*8192 + woff); \
} while (0)

    f32x16 o0 = fzero16(), o1 = fzero16();        // O^T: d-tiles 0/1, col i=il
    float m_run = -1e30f, l_loc = 0.f;

    STAGE_PAIR(0, 0);
    asm volatile("s_waitcnt vmcnt(0)" ::: "memory");
    __builtin_amdgcn_s_barrier();
    asm volatile("" ::: "memory");

    int cur = 0;
    for (int tp = 0; tp < 32; ++tp) {
        if (tp < 31) STAGE_PAIR(cur ^ 1, tp + 1);  // issue next-tile DMA; lands during compute

        const char* kb = smem + (cur*2 + st) * 8192;
        const char* vb = smem + 32768 + (cur*2 + st) * 8192;

        // S^T = K-tile x Q : two 32x32 j-tiles, K-dim 64 in 4 chunks
        f32x16 s0 = fzero16(), s1 = fzero16();
        __builtin_amdgcn_s_setprio(1);
        #pragma unroll
        for (int kc = 0; kc < 4; ++kc) {
            int c = (kc*32 + hi*16) ^ swl;
            short8 ka0 = *(const short8*)(kb + il*128 + c);
            short8 ka1 = *(const short8*)(kb + 4096 + il*128 + c);
            s0 = __builtin_amdgcn_mfma_f32_32x32x16_bf16(ka0, bq[kc], s0, 0, 0, 0);
            s1 = __builtin_amdgcn_mfma_f32_32x32x16_bf16(ka1, bq[kc], s1, 0, 0, 0);
        }
        __builtin_amdgcn_s_setprio(0);

        // tile max: depth-5 tree (max3-fusable), then cross-half shfl
        float m8[8];
        #pragma unroll
        for (int r = 0; r < 8; ++r)
            m8[r] = fmaxf(fmaxf(s0[2*r], s0[2*r+1]), fmaxf(s1[2*r], s1[2*r+1]));
        float mx = fmaxf(fmaxf(fmaxf(m8[0], m8[1]), fmaxf(m8[2], m8[3])),
                         fmaxf(fmaxf(m8[4], m8[5]), fmaxf(m8[6], m8[7])));
        mx = fmaxf(mx, __shfl_xor(mx, 32));
        if (__any(mx > m_run)) {                  // deferred rescale
            float m_new = fmaxf(m_run, mx);
            float fac = fexp2(m_run - m_new);
            l_loc *= fac;
            #pragma unroll
            for (int r = 0; r < 16; ++r) { o0[r] *= fac; o1[r] *= fac; }
            m_run = m_new;
        }
        float p0[16], p1[16];
        #pragma unroll
        for (int r = 0; r < 16; ++r) {
            p0[r] = fexp2(s0[r] - m_run);
            p1[r] = fexp2(s1[r] - m_run);
        }
        // psum: depth-5 tree instead of 32-deep serial chain
        float a8[8];
        #pragma unroll
        for (int r = 0; r < 8; ++r)
            a8[r] = (p0[2*r] + p0[2*r+1]) + (p1[2*r] + p1[2*r+1]);
        float ps = ((a8[0] + a8[1]) + (a8[2] + a8[3])) + ((a8[4] + a8[5]) + (a8[6] + a8[7]));
        l_loc += ps;

        // pack P -> bf16 pairs, permlane32_swap into PV B-frags (col=il, k-rows hi*8+0..7)
        unsigned w[16];
        #pragma unroll
        for (int t = 0; t < 2; ++t) {
            const float* pp = t ? p1 : p0;
            #pragma unroll
            for (int hh = 0; hh < 2; ++hh) {
                unsigned a = cvt_pk_bf16(pp[hh*8+0], pp[hh*8+1]);
                unsigned b = cvt_pk_bf16(pp[hh*8+2], pp[hh*8+3]);
                unsigned c = cvt_pk_bf16(pp[hh*8+4], pp[hh*8+5]);
                unsigned d = cvt_pk_bf16(pp[hh*8+6], pp[hh*8+7]);
                permswap(a, c);                   // -> [a_lo|c_lo], [a_hi|c_hi]
                permswap(b, d);
                int base = (t*2 + hh) * 4;
                w[base+0] = a; w[base+1] = b; w[base+2] = c; w[base+3] = d;
            }
        }

        // O^T += V^T x P^T : 4 j-chunks of 16, 2 d-tiles
        __builtin_amdgcn_s_setprio(1);
        #pragma unroll
        for (int jc = 0; jc < 4; ++jc) {
            union { unsigned u[4]; short8 s8; } pb;
            pb.u[0] = w[jc*4+0]; pb.u[1] = w[jc*4+1];
            pb.u[2] = w[jc*4+2]; pb.u[3] = w[jc*4+3];
            int c = (jc*32 + hi*16) ^ swl;
            short8 va0 = *(const short8*)(vb + il*128 + c);
            short8 va1 = *(const short8*)(vb + 4096 + il*128 + c);
            o0 = __builtin_amdgcn_mfma_f32_32x32x16_bf16(va0, pb.s8, o0, 0, 0, 0);
            o1 = __builtin_amdgcn_mfma_f32_32x32x16_bf16(va1, pb.s8, o1, 0, 0, 0);
        }
        __builtin_amdgcn_s_setprio(0);

        if (tp < 31) asm volatile("s_waitcnt vmcnt(0)" ::: "memory");  // next tile landed
        asm volatile("" ::: "memory");
        __builtin_amdgcn_s_barrier();             // single barrier per tile
        asm volatile("" ::: "memory");
        cur ^= 1;
    }
#undef STAGE_PAIR

    l_loc += __shfl_xor(l_loc, 32);

    // combine the two KV streams (each with its own max): st=1 writes, st=0 merges + outputs
    float* red = (float*)smem;                    // 256 slots x 34 floats = 34 KB (dead K/V region)
    int slot = ((qw*64 + lane) * 34);
    if (st == 1) {
        #pragma unroll
        for (int r = 0; r < 16; ++r) { red[slot + r] = o0[r]; red[slot + 16 + r] = o1[r]; }
        red[slot + 32] = l_loc;
        red[slot + 33] = m_run;
    }
    __syncthreads();
    if (st == 0) {
        float m1 = red[slot + 33], l1 = red[slot + 32];
        float m = fmaxf(m_run, m1);
        float f0 = fexp2(m_run - m), f1 = fexp2(m1 - m);
        float inv = 1.f / (l_loc * f0 + l1 * f1);
        float a0 = f0 * inv, a1 = f1 * inv;
        int b = bh >> 2, hh = bh & 3;
        int s = qbase + il;
        unsigned short* aop = &ao[((size_t)(b*4096 + s))*256 + hh*64];
        #pragma unroll
        for (int rr = 0; rr < 4; ++rr) {          // d = dt*32 + rr*8 + hi*4 + 0..3
            ushort4 pk0, pk1;
            pk0.x = f2bf(o0[rr*4+0]*a0 + red[slot + rr*4+0]*a1);
            pk0.y = f2bf(o0[rr*4+1]*a0 + red[slot + rr*4+1]*a1);
            pk0.z = f2bf(o0[rr*4+2]*a0 + red[slot + rr*4+2]*a1);
            pk0.w = f2bf(o0[rr*4+3]*a0 + red[slot + rr*4+3]*a1);
            *(ushort4*)&aop[rr*8 + hi*4] = pk0;
            pk1.x = f2bf(o1[rr*4+0]*a0 + red[slot + 16 + rr*4+0]*a1);
            pk1.y = f2bf(o1[rr*4+1]*a0 + red[slot + 16 + rr*4+1]*a1);
            pk1.z = f2bf(o1[rr*4+2]*a0 + red[slot + 16 + rr*4+2]*a1);
            pk1.w = f2bf(o1[rr*4+3]*a0 + red[slot + 16 + rr*4+3]*a1);
            *(ushort4*)&aop[32 + rr*8 + hi*4] = pk1;
        }
    }
}

// ------- out GEMM + bias + residual: block = 32 rows x 256 cols (ao fetched once) -------
__global__ __launch_bounds__(256) void k_out(
    const unsigned short* __restrict__ ao, const unsigned short* __restrict__ wT,
    const float* __restrict__ bout, const float* __restrict__ x,
    float* __restrict__ out) {
    int mt = blockIdx.x;                          // 512 blocks x 32 rows
    int tid = threadIdx.x;
    int wid = tid >> 6, lane = tid & 63;
    int g = lane >> 4, li = lane & 15;
    int rg = wid & 1, ch = wid >> 1;              // wave = 16 rows x 128 cols
    int m0 = mt * 32 + rg * 16;
    int row = m0 + li;
    f32x4 acc[8];
    #pragma unroll
    for (int nt = 0; nt < 8; ++nt) acc[nt] = (f32x4){0.f,0.f,0.f,0.f};
    #pragma unroll
    for (int kt = 0; kt < 8; ++kt) {
        short8 a = *(const short8*)&ao[row*256 + kt*32 + g*8];
        #pragma unroll
        for (int nt = 0; nt < 8; ++nt) {
            int nn = ch*128 + nt*16 + li;
            short8 b = *(const short8*)&wT[nn*256 + kt*32 + g*8];
            acc[nt] = __builtin_amdgcn_mfma_f32_16x16x32_bf16(a, b, acc[nt], 0, 0, 0);
        }
    }
    int b = m0 >> 12;
    int s0 = (m0 & 4095) + g*4;
    #pragma unroll
    for (int nt = 0; nt < 8; ++nt) {
        int c = ch*128 + nt*16 + li;
        float bias = bout[c];
        int base = (b*256 + c)*4096 + s0;
        float4 xr = *(const float4*)&x[base];
        float4 ov;
        ov.x = acc[nt][0] + bias + xr.x;
        ov.y = acc[nt][1] + bias + xr.y;
        ov.z = acc[nt][2] + bias + xr.z;
        ov.w = acc[nt][3] + bias + xr.w;
        *(float4*)&out[base] = ov;
    }
}

extern "C" void kernel_launch(void* const* d_in, const int* in_sizes, int n_in,
                              void* d_out, int out_size, void* d_ws, size_t ws_size,
                              hipStream_t stream) {
    (void)in_sizes; (void)n_in; (void)out_size; (void)ws_size;
    const float* x     = (const float*)d_in[0];
    const float* gamma = (const float*)d_in[1];
    const float* beta  = (const float*)d_in[2];
    const float* wqkv  = (const float*)d_in[3];
    const float* bqkv  = (const float*)d_in[4];
    const float* wout  = (const float*)d_in[5];
    const float* bout  = (const float*)d_in[6];
    float* out = (float*)d_out;

    char* ws = (char*)d_ws;
    unsigned short* h     = (unsigned short*)(ws);                    // 8 MB  [B*S][256] bf16
    unsigned short* q     = (unsigned short*)(ws + (8u<<20));         // 8 MB  [bh][S][64]
    unsigned short* kk    = (unsigned short*)(ws + (16u<<20));        // 8 MB  [bh][S][64]
    unsigned short* vT    = (unsigned short*)(ws + (24u<<20));        // 8 MB  [bh][64][S]
    unsigned short* ao    = (unsigned short*)(ws + (32u<<20));        // 8 MB  [B*S][256]
    unsigned short* wqkvT = (unsigned short*)(ws + (40u<<20));        // 384 KB [768][256]
    unsigned short* woutT = (unsigned short*)(ws + (40u<<20) + 393216);// 128 KB [256][256]
    float*          stats = (float*)(ws + (40u<<20) + 524288);        // 1 KB

    k_gn_stats<<<128, 1024, 0, stream>>>(x, stats);
    k_cvt_w<<<768, 256, 0, stream>>>(wqkv, wout, wqkvT, woutT);
    k_gn_norm<<<dim3(64, 4, 4), 256, 0, stream>>>(x, gamma, beta, stats, h);
    k_qkv<<<dim3(256, 4), 256, 0, stream>>>(h, wqkvT, bqkv, q, kk, vT);
    k_attn<<<dim3(512), 512, 0, stream>>>(q, kk, vT, ao);
    k_out<<<dim3(512), 256, 0, stream>>>(ao, woutT, bout, x, out);
}

// Round 7
// 175.095 us; speedup vs baseline: 1.1723x; 1.0311x over previous
//
#include <hip/hip_runtime.h>
#include <hip/hip_bf16.h>

// AttentionBlock: GroupNorm -> QKV -> 4-head attention (S=4096, D=64) -> out proj -> +residual
// B=4, C=256, H=W=64, S=4096, N_GROUPS=32, N_HEADS=4, D_K=64

typedef __attribute__((ext_vector_type(8))) short short8;   // 8 bf16 (4 VGPRs) MFMA A/B frag
typedef __attribute__((ext_vector_type(4))) float f32x4;    // 16x16 MFMA C/D frag
typedef __attribute__((ext_vector_type(16))) float f32x16;  // 32x32 MFMA C/D frag

__device__ __forceinline__ unsigned short f2bf(float f) {
    union { float f; unsigned u; } v; v.f = f;
    unsigned r = v.u + 0x7FFF + ((v.u >> 16) & 1);
    return (unsigned short)(r >> 16);
}

__device__ __forceinline__ unsigned cvt_pk_bf16(float lo, float hi) {
    unsigned r;
    asm("v_cvt_pk_bf16_f32 %0, %1, %2" : "=v"(r) : "v"(lo), "v"(hi));
    return r;
}

__device__ __forceinline__ void permswap(unsigned &x, unsigned &y) {
    // x' = [x_lo | y_lo], y' = [x_hi | y_hi]   (vdst hi-half <-> vsrc lo-half)
    asm("v_permlane32_swap_b32 %0, %1" : "+v"(x), "+v"(y));
}

__device__ __forceinline__ float fexp2(float x) {   // D = 2^S0
    float r;
    asm("v_exp_f32 %0, %1" : "=v"(r) : "v"(x));
    return r;
}

__device__ __forceinline__ void gl_lds16(const void* g, void* l) {
    __builtin_amdgcn_global_load_lds(
        (const __attribute__((address_space(1))) void*)(g),
        (__attribute__((address_space(3))) void*)(l), 16, 0, 0);
}

__device__ __forceinline__ f32x16 fzero16() {
    f32x16 z;
    #pragma unroll
    for (int i = 0; i < 16; ++i) z[i] = 0.f;
    return z;
}

// ---------------- GroupNorm stats: one block per (b,g), 8ch*4096 = 32768 elems ----------------
__global__ __launch_bounds__(1024) void k_gn_stats(const float* __restrict__ x,
                                                   float* __restrict__ stats) {
    int bg = blockIdx.x;                       // b*32+g ; group channels contiguous
    const float4* xp = (const float4*)(x + bg * 32768);
    float s1 = 0.f, s2 = 0.f;
    for (int i = threadIdx.x; i < 8192; i += 1024) {
        float4 v = xp[i];
        s1 += v.x + v.y + v.z + v.w;
        s2 += v.x*v.x + v.y*v.y + v.z*v.z + v.w*v.w;
    }
    #pragma unroll
    for (int off = 32; off; off >>= 1) {
        s1 += __shfl_down(s1, off);
        s2 += __shfl_down(s2, off);
    }
    __shared__ float r1[16], r2[16];
    int wid = threadIdx.x >> 6;
    if ((threadIdx.x & 63) == 0) { r1[wid] = s1; r2[wid] = s2; }
    __syncthreads();
    if (threadIdx.x == 0) {
        float a = 0.f, b = 0.f;
        #pragma unroll
        for (int i = 0; i < 16; ++i) { a += r1[i]; b += r2[i]; }
        float mean = a * (1.f/32768.f);
        float var  = b * (1.f/32768.f) - mean*mean;
        stats[bg*2]   = mean;
        stats[bg*2+1] = rsqrtf(var + 1e-5f);
    }
}

// ------------- convert + transpose weights to bf16 [N][K] so B-frags are contiguous -------------
__global__ void k_cvt_w(const float* __restrict__ wqkv, const float* __restrict__ wout,
                        unsigned short* __restrict__ wqkvT, unsigned short* __restrict__ woutT) {
    int i = blockIdx.x * 256 + threadIdx.x;
    if (i < 196608) {                       // w_qkv [256][768] -> [768][256]
        int k = i / 768, n = i - k * 768;
        wqkvT[n*256 + k] = f2bf(wqkv[i]);
    }
    if (i < 65536) {                        // w_out [256][256] -> [256][256]^T
        int k = i >> 8, n = i & 255;
        woutT[n*256 + k] = f2bf(wout[i]);
    }
}

// ------- normalize + transpose: x[b][c][s] fp32 -> h[b][s][c] bf16 via 64x64 LDS tile -------
__global__ __launch_bounds__(256) void k_gn_norm(
    const float* __restrict__ x, const float* __restrict__ gamma,
    const float* __restrict__ beta, const float* __restrict__ stats,
    unsigned short* __restrict__ h) {
    __shared__ unsigned short t[64][72];          // pad 8 -> decent bank spread
    int s0 = blockIdx.x * 64, c0 = blockIdx.y * 64, b = blockIdx.z;
    int tid = threadIdx.x;
    int sl = (tid & 15) * 4;                      // float4 along s
    int cr = tid >> 4;
    #pragma unroll
    for (int p = 0; p < 4; ++p) {
        int c = c0 + cr + p * 16;
        float4 v = *(const float4*)&x[(b*256 + c)*4096 + s0 + sl];
        int sg = (b*32 + (c >> 3)) * 2;
        float mean = stats[sg], rstd = stats[sg+1];
        float sa = rstd * gamma[c];
        float sb = beta[c] - mean * sa;
        ushort4 pk;
        pk.x = f2bf(v.x*sa + sb); pk.y = f2bf(v.y*sa + sb);
        pk.z = f2bf(v.z*sa + sb); pk.w = f2bf(v.w*sa + sb);
        *(ushort4*)&t[cr + p*16][sl] = pk;
    }
    __syncthreads();
    int sr = tid >> 2;                            // 0..63 (s row)
    int cc = (tid & 3) * 16;                      // 16 channels per thread
    unsigned rr[8];
    #pragma unroll
    for (int j = 0; j < 8; ++j)
        rr[j] = (unsigned)t[cc + 2*j][sr] | ((unsigned)t[cc + 2*j + 1][sr] << 16);
    unsigned short* hp = &h[(b*4096 + s0 + sr)*256 + c0];
    *(uint4*)&hp[cc]     = make_uint4(rr[0], rr[1], rr[2], rr[3]);
    *(uint4*)&hp[cc + 8] = make_uint4(rr[4], rr[5], rr[6], rr[7]);
}

// ---------------- QKV GEMM: h[16384][256] @ wqkvT -> q,k [bh][S][64], vT [bh][64][S] ----------------
// Q gets 0.125 * log2(e) folded in (attention softmax runs in exp2 domain).
__global__ __launch_bounds__(256) void k_qkv(
    const unsigned short* __restrict__ h, const unsigned short* __restrict__ wT,
    const float* __restrict__ bqkv,
    unsigned short* __restrict__ q, unsigned short* __restrict__ kk,
    unsigned short* __restrict__ vT) {
    int mt = blockIdx.x, head = blockIdx.y;
    int tid = threadIdx.x;
    int wid = tid >> 6, lane = tid & 63;
    int g = lane >> 4, li = lane & 15;
    int m0 = mt * 64 + wid * 16;
    int row = m0 + li;
    f32x4 acc[12];
    #pragma unroll
    for (int nt = 0; nt < 12; ++nt) acc[nt] = (f32x4){0.f,0.f,0.f,0.f};
    #pragma unroll
    for (int kt = 0; kt < 8; ++kt) {
        short8 a = *(const short8*)&h[row*256 + kt*32 + g*8];
        #pragma unroll
        for (int nt = 0; nt < 12; ++nt) {
            int n = head*192 + nt*16 + li;
            short8 b = *(const short8*)&wT[n*256 + kt*32 + g*8];
            acc[nt] = __builtin_amdgcn_mfma_f32_16x16x32_bf16(a, b, acc[nt], 0, 0, 0);
        }
    }
    int b = m0 >> 12;
    int s0 = m0 & 4095;
    int bh = b*4 + head;
    #pragma unroll
    for (int nt = 0; nt < 12; ++nt) {
        int ng = head*192 + nt*16 + li;
        float bias = bqkv[ng];
        int d = (nt & 3)*16 + li;
        if ((nt >> 2) == 2) {                         // V -> transposed [bh][d][s]
            ushort4 pk;
            pk.x = f2bf(acc[nt][0] + bias); pk.y = f2bf(acc[nt][1] + bias);
            pk.z = f2bf(acc[nt][2] + bias); pk.w = f2bf(acc[nt][3] + bias);
            *(ushort4*)&vT[(bh*64 + d)*4096 + s0 + g*4] = pk;
        } else if ((nt >> 2) == 0) {                  // Q (scale 0.125*log2e folded in)
            #pragma unroll
            for (int r = 0; r < 4; ++r)
                q[(bh*4096 + s0 + g*4 + r)*64 + d] = f2bf((acc[nt][r] + bias) * 0.1803368801f);
        } else {                                      // K
            #pragma unroll
            for (int r = 0; r < 4; ++r)
                kk[(bh*4096 + s0 + g*4 + r)*64 + d] = f2bf(acc[nt][r] + bias);
        }
    }
}

// ---------------- flash attention, 32x32x16 MFMA, KV-stream split -----------------------------
// Softmax restructured: C-init = -m folds the subtract into the QK MFMA; exp2 speculatively with
// the stale max (airtight bound P <= 16 via THR=4 check on Pmax), rare correction P*=1/Pmax;
// l computed on the MFMA pipe via an all-ones A-operand into a third accumulator.
__global__ __launch_bounds__(512, 4) void k_attn(
    const unsigned short* __restrict__ q, const unsigned short* __restrict__ kk,
    const unsigned short* __restrict__ vT, unsigned short* __restrict__ ao) {
    __shared__ __align__(16) char smem[65536];    // [dbuf][stream] K 8KB x4 | V 8KB x4

    int n = blockIdx.x;                           // 512 blocks; XCD = n & 7 (round-robin dispatch)
    int qt = n >> 4;
    int bh = ((n & 7) << 1) | ((n >> 3) & 1);     // 2 heads per XCD -> K/V fits 4MB L2
    int tid = threadIdx.x;
    int wid = tid >> 6, lane = tid & 63;
    int qw = wid & 3, st = wid >> 2;
    int hi = lane >> 5, il = lane & 31;
    int swl = (il & 7) << 4;

    int qbase = qt * 128 + qw * 32;
    int qrow = bh * 4096 + qbase + il;
    short8 bq[4];                                 // Q B-frags: col=il, k=kc*16+hi*8..
    #pragma unroll
    for (int kc = 0; kc < 4; ++kc)
        bq[kc] = *(const short8*)&q[qrow*64 + kc*16 + hi*8];

    short8 ones;                                  // all-ones bf16 A-frag for the l-MFMA
    #pragma unroll
    for (int i = 0; i < 8; ++i) ones[i] = (short)0x3F80;

    // staging geometry: 512 threads cover one 8KB tile (16B each)
    unsigned p16  = tid * 16;
    unsigned row0 = p16 >> 7;                     // 0..63
    unsigned sw   = (row0 & 7) << 4;
    unsigned ks0  = p16 ^ sw;                     // K tile-local swizzled source byte
    unsigned vc0  = (p16 & 127u) ^ sw;            // V column byte within row
    const char* kbase = (const char*)kk + (size_t)bh * 524288;
    const char* vbase = (const char*)vT + (size_t)(bh*64 + row0) * 8192;
    unsigned woff = wid * 1024;

#define STAGE_PAIR(d, pair) do {                                             \
    const char* _k0 = kbase + (size_t)(2*(pair)) * 8192;                     \
    size_t _vo = (size_t)(2*(pair)) * 128;                                   \
    gl_lds16(_k0 + ks0,              smem + ((d)*2+0)*8192 + woff);          \
    gl_lds16(_k0 + 8192 + ks0,       smem + ((d)*2+1)*8192 + woff);          \
    gl_lds16(vbase + _vo + vc0,       smem + 32768 + ((d)*2+0)*8192 + woff); \
    gl_lds16(vbase + _vo + 128 + vc0, smem + 32768 + ((d)*2+1)*8192 + woff); \
} while (0)

    f32x16 o0 = fzero16(), o1 = fzero16(), accl = fzero16();
    float m_run = 0.f;                            // stale-max in exp2 domain; P <= 16 guaranteed

    STAGE_PAIR(0, 0);
    asm volatile("s_waitcnt vmcnt(0)" ::: "memory");
    __builtin_amdgcn_s_barrier();
    asm volatile("" ::: "memory");

    int cur = 0;
    for (int tp = 0; tp < 32; ++tp) {
        if (tp < 31) STAGE_PAIR(cur ^ 1, tp + 1);  // issue next-tile DMA; lands during compute

        const char* kb = smem + (cur*2 + st) * 8192;
        const char* vb = smem + 32768 + (cur*2 + st) * 8192;

        // (S - m) directly out of the MFMA: C-init = -m_run
        float nm = -m_run;
        f32x16 p0, p1;
        #pragma unroll
        for (int r = 0; r < 16; ++r) { p0[r] = nm; p1[r] = nm; }
        __builtin_amdgcn_s_setprio(1);
        #pragma unroll
        for (int kc = 0; kc < 4; ++kc) {
            int c = (kc*32 + hi*16) ^ swl;
            short8 ka0 = *(const short8*)(kb + il*128 + c);
            short8 ka1 = *(const short8*)(kb + 4096 + il*128 + c);
            p0 = __builtin_amdgcn_mfma_f32_32x32x16_bf16(ka0, bq[kc], p0, 0, 0, 0);
            p1 = __builtin_amdgcn_mfma_f32_32x32x16_bf16(ka1, bq[kc], p1, 0, 0, 0);
        }
        __builtin_amdgcn_s_setprio(0);

        // speculative P = exp2(S - m_run), in place
        #pragma unroll
        for (int r = 0; r < 16; ++r) {
            p0[r] = fexp2(p0[r]);
            p1[r] = fexp2(p1[r]);
        }
        // Pmax tree (depth 5); rescale only if P would exceed 2^4
        float m8[8];
        #pragma unroll
        for (int r = 0; r < 8; ++r)
            m8[r] = fmaxf(fmaxf(p0[2*r], p0[2*r+1]), fmaxf(p1[2*r], p1[2*r+1]));
        float pm = fmaxf(fmaxf(fmaxf(m8[0], m8[1]), fmaxf(m8[2], m8[3])),
                         fmaxf(fmaxf(m8[4], m8[5]), fmaxf(m8[6], m8[7])));
        if (__any(pm > 16.f)) {                   // rare: max grew by > 4 (exp2 domain)
            pm = fmaxf(pm, __shfl_xor(pm, 32));   // row max across lane halves
            float fac = 1.f / pm;
            m_run += log2f(pm);
            accl[0] *= fac;                       // only element 0 is ever read
            #pragma unroll
            for (int r = 0; r < 16; ++r) {
                o0[r] *= fac; o1[r] *= fac;
                p0[r] *= fac; p1[r] *= fac;
            }
        }

        // pack P -> bf16 B-frags (cvt_pk + permlane32_swap) fused with PV + l MFMAs
        __builtin_amdgcn_s_setprio(1);
        #pragma unroll
        for (int jc = 0; jc < 4; ++jc) {
            const int hh = jc & 1;
            float e0, e1, e2, e3, e4, e5, e6, e7;
            if (jc < 2) {
                e0 = p0[hh*8+0]; e1 = p0[hh*8+1]; e2 = p0[hh*8+2]; e3 = p0[hh*8+3];
                e4 = p0[hh*8+4]; e5 = p0[hh*8+5]; e6 = p0[hh*8+6]; e7 = p0[hh*8+7];
            } else {
                e0 = p1[hh*8+0]; e1 = p1[hh*8+1]; e2 = p1[hh*8+2]; e3 = p1[hh*8+3];
                e4 = p1[hh*8+4]; e5 = p1[hh*8+5]; e6 = p1[hh*8+6]; e7 = p1[hh*8+7];
            }
            unsigned a = cvt_pk_bf16(e0, e1);
            unsigned b = cvt_pk_bf16(e2, e3);
            unsigned c = cvt_pk_bf16(e4, e5);
            unsigned d = cvt_pk_bf16(e6, e7);
            permswap(a, c);                       // -> [a_lo|c_lo], [a_hi|c_hi]
            permswap(b, d);
            union { unsigned u[4]; short8 s8; } pb;
            pb.u[0] = a; pb.u[1] = b; pb.u[2] = c; pb.u[3] = d;
            int co = (jc*32 + hi*16) ^ swl;
            short8 va0 = *(const short8*)(vb + il*128 + co);
            short8 va1 = *(const short8*)(vb + 4096 + il*128 + co);
            o0   = __builtin_amdgcn_mfma_f32_32x32x16_bf16(va0, pb.s8, o0, 0, 0, 0);
            o1   = __builtin_amdgcn_mfma_f32_32x32x16_bf16(va1, pb.s8, o1, 0, 0, 0);
            accl = __builtin_amdgcn_mfma_f32_32x32x16_bf16(ones, pb.s8, accl, 0, 0, 0);
        }
        __builtin_amdgcn_s_setprio(0);

        if (tp < 31) asm volatile("s_waitcnt vmcnt(0)" ::: "memory");  // next tile landed
        asm volatile("" ::: "memory");
        __builtin_amdgcn_s_barrier();             // single barrier per tile
        asm volatile("" ::: "memory");
        cur ^= 1;
    }
#undef STAGE_PAIR

    float l_loc = accl[0];                        // full row sum (MFMA k-dim spans both halves)

    // combine the two KV streams (each with its own max): st=1 writes, st=0 merges + outputs
    float* red = (float*)smem;                    // 256 slots x 34 floats = 34 KB (dead K/V region)
    int slot = ((qw*64 + lane) * 34);
    if (st == 1) {
        #pragma unroll
        for (int r = 0; r < 16; ++r) { red[slot + r] = o0[r]; red[slot + 16 + r] = o1[r]; }
        red[slot + 32] = l_loc;
        red[slot + 33] = m_run;
    }
    __syncthreads();
    if (st == 0) {
        float m1 = red[slot + 33], l1 = red[slot + 32];
        float m = fmaxf(m_run, m1);
        float f0 = fexp2(m_run - m), f1 = fexp2(m1 - m);
        float inv = 1.f / (l_loc * f0 + l1 * f1);
        float a0 = f0 * inv, a1 = f1 * inv;
        int b = bh >> 2, hh = bh & 3;
        int s = qbase + il;
        unsigned short* aop = &ao[((size_t)(b*4096 + s))*256 + hh*64];
        #pragma unroll
        for (int rr = 0; rr < 4; ++rr) {          // d = dt*32 + rr*8 + hi*4 + 0..3
            ushort4 pk0, pk1;
            pk0.x = f2bf(o0[rr*4+0]*a0 + red[slot + rr*4+0]*a1);
            pk0.y = f2bf(o0[rr*4+1]*a0 + red[slot + rr*4+1]*a1);
            pk0.z = f2bf(o0[rr*4+2]*a0 + red[slot + rr*4+2]*a1);
            pk0.w = f2bf(o0[rr*4+3]*a0 + red[slot + rr*4+3]*a1);
            *(ushort4*)&aop[rr*8 + hi*4] = pk0;
            pk1.x = f2bf(o1[rr*4+0]*a0 + red[slot + 16 + rr*4+0]*a1);
            pk1.y = f2bf(o1[rr*4+1]*a0 + red[slot + 16 + rr*4+1]*a1);
            pk1.z = f2bf(o1[rr*4+2]*a0 + red[slot + 16 + rr*4+2]*a1);
            pk1.w = f2bf(o1[rr*4+3]*a0 + red[slot + 16 + rr*4+3]*a1);
            *(ushort4*)&aop[32 + rr*8 + hi*4] = pk1;
        }
    }
}

// ------- out GEMM + bias + residual: block = 32 rows x 256 cols (ao fetched once) -------
__global__ __launch_bounds__(256) void k_out(
    const unsigned short* __restrict__ ao, const unsigned short* __restrict__ wT,
    const float* __restrict__ bout, const float* __restrict__ x,
    float* __restrict__ out) {
    int mt = blockIdx.x;                          // 512 blocks x 32 rows
    int tid = threadIdx.x;
    int wid = tid >> 6, lane = tid & 63;
    int g = lane >> 4, li = lane & 15;
    int rg = wid & 1, ch = wid >> 1;              // wave = 16 rows x 128 cols
    int m0 = mt * 32 + rg * 16;
    int row = m0 + li;
    f32x4 acc[8];
    #pragma unroll
    for (int nt = 0; nt < 8; ++nt) acc[nt] = (f32x4){0.f,0.f,0.f,0.f};
    #pragma unroll
    for (int kt = 0; kt < 8; ++kt) {
        short8 a = *(const short8*)&ao[row*256 + kt*32 + g*8];
        #pragma unroll
        for (int nt = 0; nt < 8; ++nt) {
            int nn = ch*128 + nt*16 + li;
            short8 b = *(const short8*)&wT[nn*256 + kt*32 + g*8];
            acc[nt] = __builtin_amdgcn_mfma_f32_16x16x32_bf16(a, b, acc[nt], 0, 0, 0);
        }
    }
    int b = m0 >> 12;
    int s0 = (m0 & 4095) + g*4;
    #pragma unroll
    for (int nt = 0; nt < 8; ++nt) {
        int c = ch*128 + nt*16 + li;
        float bias = bout[c];
        int base = (b*256 + c)*4096 + s0;
        float4 xr = *(const float4*)&x[base];
        float4 ov;
        ov.x = acc[nt][0] + bias + xr.x;
        ov.y = acc[nt][1] + bias + xr.y;
        ov.z = acc[nt][2] + bias + xr.z;
        ov.w = acc[nt][3] + bias + xr.w;
        *(float4*)&out[base] = ov;
    }
}

extern "C" void kernel_launch(void* const* d_in, const int* in_sizes, int n_in,
                              void* d_out, int out_size, void* d_ws, size_t ws_size,
                              hipStream_t stream) {
    (void)in_sizes; (void)n_in; (void)out_size; (void)ws_size;
    const float* x     = (const float*)d_in[0];
    const float* gamma = (const float*)d_in[1];
    const float* beta  = (const float*)d_in[2];
    const float* wqkv  = (const float*)d_in[3];
    const float* bqkv  = (const float*)d_in[4];
    const float* wout  = (const float*)d_in[5];
    const float* bout  = (const float*)d_in[6];
    float* out = (float*)d_out;

    char* ws = (char*)d_ws;
    unsigned short* h     = (unsigned short*)(ws);                    // 8 MB  [B*S][256] bf16
    unsigned short* q     = (unsigned short*)(ws + (8u<<20));         // 8 MB  [bh][S][64]
    unsigned short* kk    = (unsigned short*)(ws + (16u<<20));        // 8 MB  [bh][S][64]
    unsigned short* vT    = (unsigned short*)(ws + (24u<<20));        // 8 MB  [bh][64][S]
    unsigned short* ao    = (unsigned short*)(ws + (32u<<20));        // 8 MB  [B*S][256]
    unsigned short* wqkvT = (unsigned short*)(ws + (40u<<20));        // 384 KB [768][256]
    unsigned short* woutT = (unsigned short*)(ws + (40u<<20) + 393216);// 128 KB [256][256]
    float*          stats = (float*)(ws + (40u<<20) + 524288);        // 1 KB

    k_gn_stats<<<128, 1024, 0, stream>>>(x, stats);
    k_cvt_w<<<768, 256, 0, stream>>>(wqkv, wout, wqkvT, woutT);
    k_gn_norm<<<dim3(64, 4, 4), 256, 0, stream>>>(x, gamma, beta, stats, h);
    k_qkv<<<dim3(256, 4), 256, 0, stream>>>(h, wqkvT, bqkv, q, kk, vT);
    k_attn<<<dim3(512), 512, 0, stream>>>(q, kk, vT, ao);
    k_out<<<dim3(512), 256, 0, stream>>>(ao, woutT, bout, x, out);
}

// Round 8
// 170.438 us; speedup vs baseline: 1.2043x; 1.0273x over previous
//
#include <hip/hip_runtime.h>
#include <hip/hip_bf16.h>

// AttentionBlock: GroupNorm -> QKV -> 4-head attention (S=4096, D=64) -> out proj -> +residual
// B=4, C=256, H=W=64, S=4096, N_GROUPS=32, N_HEADS=4, D_K=64

typedef __attribute__((ext_vector_type(8))) short short8;   // 8 bf16 (4 VGPRs) MFMA A/B frag
typedef __attribute__((ext_vector_type(4))) float f32x4;    // 16x16 MFMA C/D frag
typedef __attribute__((ext_vector_type(16))) float f32x16;  // 32x32 MFMA C/D frag

__device__ __forceinline__ unsigned short f2bf(float f) {
    union { float f; unsigned u; } v; v.f = f;
    unsigned r = v.u + 0x7FFF + ((v.u >> 16) & 1);
    return (unsigned short)(r >> 16);
}

__device__ __forceinline__ unsigned cvt_pk_bf16(float lo, float hi) {
    unsigned r;
    asm("v_cvt_pk_bf16_f32 %0, %1, %2" : "=v"(r) : "v"(lo), "v"(hi));
    return r;
}

__device__ __forceinline__ void permswap(unsigned &x, unsigned &y) {
    // x' = [x_lo | y_lo], y' = [x_hi | y_hi]   (vdst hi-half <-> vsrc lo-half)
    asm("v_permlane32_swap_b32 %0, %1" : "+v"(x), "+v"(y));
}

__device__ __forceinline__ float fexp2(float x) {   // D = 2^S0
    float r;
    asm("v_exp_f32 %0, %1" : "=v"(r) : "v"(x));
    return r;
}

__device__ __forceinline__ void gl_lds16(const void* g, void* l) {
    __builtin_amdgcn_global_load_lds(
        (const __attribute__((address_space(1))) void*)(g),
        (__attribute__((address_space(3))) void*)(l), 16, 0, 0);
}

__device__ __forceinline__ f32x16 fzero16() {
    f32x16 z;
    #pragma unroll
    for (int i = 0; i < 16; ++i) z[i] = 0.f;
    return z;
}

// -------- fat kernel: blocks 0-127 GroupNorm stats; blocks 128-319 weight convert --------
__global__ __launch_bounds__(1024) void k_pre(
    const float* __restrict__ x, float* __restrict__ stats,
    const float* __restrict__ wqkv, const float* __restrict__ wout,
    unsigned short* __restrict__ wqkvT, unsigned short* __restrict__ woutT) {
    if (blockIdx.x < 128) {
        int bg = blockIdx.x;                       // b*32+g ; group channels contiguous
        const float4* xp = (const float4*)(x + bg * 32768);
        float s1 = 0.f, s2 = 0.f;
        for (int i = threadIdx.x; i < 8192; i += 1024) {
            float4 v = xp[i];
            s1 += v.x + v.y + v.z + v.w;
            s2 += v.x*v.x + v.y*v.y + v.z*v.z + v.w*v.w;
        }
        #pragma unroll
        for (int off = 32; off; off >>= 1) {
            s1 += __shfl_down(s1, off);
            s2 += __shfl_down(s2, off);
        }
        __shared__ float r1[16], r2[16];
        int wid = threadIdx.x >> 6;
        if ((threadIdx.x & 63) == 0) { r1[wid] = s1; r2[wid] = s2; }
        __syncthreads();
        if (threadIdx.x == 0) {
            float a = 0.f, b = 0.f;
            #pragma unroll
            for (int i = 0; i < 16; ++i) { a += r1[i]; b += r2[i]; }
            float mean = a * (1.f/32768.f);
            float var  = b * (1.f/32768.f) - mean*mean;
            stats[bg*2]   = mean;
            stats[bg*2+1] = rsqrtf(var + 1e-5f);
        }
    } else {
        int i = (blockIdx.x - 128) * 1024 + threadIdx.x;
        if (i < 196608) {                       // w_qkv [256][768] -> [768][256]
            int k = i / 768, n = i - k * 768;
            wqkvT[n*256 + k] = f2bf(wqkv[i]);
        }
        if (i < 65536) {                        // w_out [256][256] -> [256][256]^T
            int k = i >> 8, n = i & 255;
            woutT[n*256 + k] = f2bf(wout[i]);
        }
    }
}

// -------- fused GroupNorm-apply + QKV GEMM --------
// block = 512 thr, 64 s-rows x all 768 outputs. Phase 1: normalize x -> bf16 h-tile in LDS
// (4 slabs of 64 channels, verified 64x64 transpose pattern). Phase 2: verified QKV GEMM with
// A-frags from LDS. Q gets 0.125*log2(e) folded in; K plain; V stored transposed.
__global__ __launch_bounds__(512, 2) void k_qkvf(
    const float* __restrict__ x, const float* __restrict__ gamma,
    const float* __restrict__ beta, const float* __restrict__ stats,
    const unsigned short* __restrict__ wT, const float* __restrict__ bqkv,
    unsigned short* __restrict__ q, unsigned short* __restrict__ kk,
    unsigned short* __restrict__ vT) {
    __shared__ unsigned short t[64][72];          // c-slab staging (verified pattern)
    __shared__ unsigned short lds_h[64][272];     // h-tile [s][c], pad->bank spread

    int m0 = blockIdx.x * 64;                     // global row base (b*4096 + s0)
    int b = m0 >> 12;
    int s0 = m0 & 4095;
    int tid = threadIdx.x;

    // Phase 1: 4 slabs of 64 channels
    #pragma unroll
    for (int cb = 0; cb < 4; ++cb) {
        int c0 = cb * 64;
        #pragma unroll
        for (int k = 0; k < 2; ++k) {
            int u = tid + k * 512;                // 1024 units: 64 c x 16 float4-slots
            int cr = u >> 4;
            int sl = (u & 15) * 4;
            int c = c0 + cr;
            float4 v = *(const float4*)&x[(b*256 + c)*4096 + s0 + sl];
            int sg = (b*32 + (c >> 3)) * 2;
            float mean = stats[sg], rstd = stats[sg+1];
            float sa = rstd * gamma[c];
            float sb = beta[c] - mean * sa;
            ushort4 pk;
            pk.x = f2bf(v.x*sa + sb); pk.y = f2bf(v.y*sa + sb);
            pk.z = f2bf(v.z*sa + sb); pk.w = f2bf(v.w*sa + sb);
            *(ushort4*)&t[cr][sl] = pk;
        }
        __syncthreads();
        int sr = tid >> 3;                        // 0..63 s-row
        int cc8 = (tid & 7) * 8;                  // 8 channels per thread
        unsigned rr[4];
        #pragma unroll
        for (int j = 0; j < 4; ++j)
            rr[j] = (unsigned)t[cc8 + 2*j][sr] | ((unsigned)t[cc8 + 2*j + 1][sr] << 16);
        *(uint4*)&lds_h[sr][c0 + cc8] = make_uint4(rr[0], rr[1], rr[2], rr[3]);
        __syncthreads();
    }

    // Phase 2: GEMM 64 x 768, K=256
    int wid = tid >> 6, lane = tid & 63;
    int g = lane >> 4, li = lane & 15;
    int rg = wid & 3, cg = wid >> 2;              // wave = 16 rows x 384 cols
    int rowl = rg * 16 + li;
    f32x4 acc[24];
    #pragma unroll
    for (int nt = 0; nt < 24; ++nt) acc[nt] = (f32x4){0.f,0.f,0.f,0.f};
    #pragma unroll
    for (int kt = 0; kt < 8; ++kt) {
        short8 a = *(const short8*)&lds_h[rowl][kt*32 + g*8];
        #pragma unroll
        for (int nt = 0; nt < 24; ++nt) {
            int n = cg*384 + nt*16 + li;
            short8 bb = *(const short8*)&wT[n*256 + kt*32 + g*8];
            acc[nt] = __builtin_amdgcn_mfma_f32_16x16x32_bf16(a, bb, acc[nt], 0, 0, 0);
        }
    }
    int m0w = m0 + rg * 16;
    int s0w = m0w & 4095;
    #pragma unroll
    for (int nt = 0; nt < 24; ++nt) {
        int ng = cg*384 + nt*16 + li;
        int head = cg*2 + nt/12;
        int ntl = nt % 12;
        int bh = b*4 + head;
        float bias = bqkv[ng];
        int d = (ntl & 3)*16 + li;
        if ((ntl >> 2) == 2) {                        // V -> transposed [bh][d][s]
            ushort4 pk;
            pk.x = f2bf(acc[nt][0] + bias); pk.y = f2bf(acc[nt][1] + bias);
            pk.z = f2bf(acc[nt][2] + bias); pk.w = f2bf(acc[nt][3] + bias);
            *(ushort4*)&vT[(bh*64 + d)*4096 + s0w + g*4] = pk;
        } else if ((ntl >> 2) == 0) {                 // Q (scale 0.125*log2e folded in)
            #pragma unroll
            for (int r = 0; r < 4; ++r)
                q[(bh*4096 + s0w + g*4 + r)*64 + d] = f2bf((acc[nt][r] + bias) * 0.1803368801f);
        } else {                                      // K
            #pragma unroll
            for (int r = 0; r < 4; ++r)
                kk[(bh*4096 + s0w + g*4 + r)*64 + d] = f2bf(acc[nt][r] + bias);
        }
    }
}

// ---------------- flash attention, 32x32x16 MFMA, KV-stream split -----------------------------
// Softmax: C-init = -m folds the subtract into the QK MFMA; speculative exp2 with stale max
// (bound P <= 16 via THR=4 on Pmax), rare correction; l via ones-MFMA on the matrix pipe.
__global__ __launch_bounds__(512, 4) void k_attn(
    const unsigned short* __restrict__ q, const unsigned short* __restrict__ kk,
    const unsigned short* __restrict__ vT, unsigned short* __restrict__ ao) {
    __shared__ __align__(16) char smem[65536];    // [dbuf][stream] K 8KB x4 | V 8KB x4

    int n = blockIdx.x;                           // 512 blocks; XCD = n & 7 (round-robin dispatch)
    int qt = n >> 4;
    int bh = ((n & 7) << 1) | ((n >> 3) & 1);     // 2 heads per XCD -> K/V fits 4MB L2
    int tid = threadIdx.x;
    int wid = tid >> 6, lane = tid & 63;
    int qw = wid & 3, st = wid >> 2;
    int hi = lane >> 5, il = lane & 31;
    int swl = (il & 7) << 4;

    int qbase = qt * 128 + qw * 32;
    int qrow = bh * 4096 + qbase + il;
    short8 bq[4];                                 // Q B-frags: col=il, k=kc*16+hi*8..
    #pragma unroll
    for (int kc = 0; kc < 4; ++kc)
        bq[kc] = *(const short8*)&q[qrow*64 + kc*16 + hi*8];

    short8 ones;                                  // all-ones bf16 A-frag for the l-MFMA
    #pragma unroll
    for (int i = 0; i < 8; ++i) ones[i] = (short)0x3F80;

    // staging geometry: 512 threads cover one 8KB tile (16B each)
    unsigned p16  = tid * 16;
    unsigned row0 = p16 >> 7;                     // 0..63
    unsigned sw   = (row0 & 7) << 4;
    unsigned ks0  = p16 ^ sw;                     // K tile-local swizzled source byte
    unsigned vc0  = (p16 & 127u) ^ sw;            // V column byte within row
    const char* kbase = (const char*)kk + (size_t)bh * 524288;
    const char* vbase = (const char*)vT + (size_t)(bh*64 + row0) * 8192;
    unsigned woff = wid * 1024;

#define STAGE_PAIR(d, pair) do {                                             \
    const char* _k0 = kbase + (size_t)(2*(pair)) * 8192;                     \
    size_t _vo = (size_t)(2*(pair)) * 128;                                   \
    gl_lds16(_k0 + ks0,              smem + ((d)*2+0)*8192 + woff);          \
    gl_lds16(_k0 + 8192 + ks0,       smem + ((d)*2+1)*8192 + woff);          \
    gl_lds16(vbase + _vo + vc0,       smem + 32768 + ((d)*2+0)*8192 + woff); \
    gl_lds16(vbase + _vo + 128 + vc0, smem + 32768 + ((d)*2+1)*8192 + woff); \
} while (0)

    f32x16 o0 = fzero16(), o1 = fzero16(), accl = fzero16();
    float m_run = 0.f;                            // stale-max in exp2 domain; P <= 16 guaranteed

    STAGE_PAIR(0, 0);
    asm volatile("s_waitcnt vmcnt(0)" ::: "memory");
    __builtin_amdgcn_s_barrier();
    asm volatile("" ::: "memory");

    int cur = 0;
    for (int tp = 0; tp < 32; ++tp) {
        if (tp < 31) STAGE_PAIR(cur ^ 1, tp + 1);  // issue next-tile DMA; lands during compute

        const char* kb = smem + (cur*2 + st) * 8192;
        const char* vb = smem + 32768 + (cur*2 + st) * 8192;

        // (S - m) directly out of the MFMA: C-init = -m_run
        float nm = -m_run;
        f32x16 p0, p1;
        #pragma unroll
        for (int r = 0; r < 16; ++r) { p0[r] = nm; p1[r] = nm; }
        __builtin_amdgcn_s_setprio(1);
        #pragma unroll
        for (int kc = 0; kc < 4; ++kc) {
            int c = (kc*32 + hi*16) ^ swl;
            short8 ka0 = *(const short8*)(kb + il*128 + c);
            short8 ka1 = *(const short8*)(kb + 4096 + il*128 + c);
            p0 = __builtin_amdgcn_mfma_f32_32x32x16_bf16(ka0, bq[kc], p0, 0, 0, 0);
            p1 = __builtin_amdgcn_mfma_f32_32x32x16_bf16(ka1, bq[kc], p1, 0, 0, 0);
        }
        __builtin_amdgcn_s_setprio(0);

        // speculative P = exp2(S - m_run), in place
        #pragma unroll
        for (int r = 0; r < 16; ++r) {
            p0[r] = fexp2(p0[r]);
            p1[r] = fexp2(p1[r]);
        }
        // Pmax tree (depth 5); rescale only if P would exceed 2^4
        float m8[8];
        #pragma unroll
        for (int r = 0; r < 8; ++r)
            m8[r] = fmaxf(fmaxf(p0[2*r], p0[2*r+1]), fmaxf(p1[2*r], p1[2*r+1]));
        float pm = fmaxf(fmaxf(fmaxf(m8[0], m8[1]), fmaxf(m8[2], m8[3])),
                         fmaxf(fmaxf(m8[4], m8[5]), fmaxf(m8[6], m8[7])));
        if (__any(pm > 16.f)) {                   // rare: max grew by > 4 (exp2 domain)
            pm = fmaxf(pm, __shfl_xor(pm, 32));   // row max across lane halves
            float fac = 1.f / pm;
            m_run += log2f(pm);
            accl[0] *= fac;                       // only element 0 is ever read
            #pragma unroll
            for (int r = 0; r < 16; ++r) {
                o0[r] *= fac; o1[r] *= fac;
                p0[r] *= fac; p1[r] *= fac;
            }
        }

        // pack P -> bf16 B-frags (cvt_pk + permlane32_swap) fused with PV + l MFMAs
        __builtin_amdgcn_s_setprio(1);
        #pragma unroll
        for (int jc = 0; jc < 4; ++jc) {
            const int hh = jc & 1;
            float e0, e1, e2, e3, e4, e5, e6, e7;
            if (jc < 2) {
                e0 = p0[hh*8+0]; e1 = p0[hh*8+1]; e2 = p0[hh*8+2]; e3 = p0[hh*8+3];
                e4 = p0[hh*8+4]; e5 = p0[hh*8+5]; e6 = p0[hh*8+6]; e7 = p0[hh*8+7];
            } else {
                e0 = p1[hh*8+0]; e1 = p1[hh*8+1]; e2 = p1[hh*8+2]; e3 = p1[hh*8+3];
                e4 = p1[hh*8+4]; e5 = p1[hh*8+5]; e6 = p1[hh*8+6]; e7 = p1[hh*8+7];
            }
            unsigned a = cvt_pk_bf16(e0, e1);
            unsigned b = cvt_pk_bf16(e2, e3);
            unsigned c = cvt_pk_bf16(e4, e5);
            unsigned d = cvt_pk_bf16(e6, e7);
            permswap(a, c);                       // -> [a_lo|c_lo], [a_hi|c_hi]
            permswap(b, d);
            union { unsigned u[4]; short8 s8; } pb;
            pb.u[0] = a; pb.u[1] = b; pb.u[2] = c; pb.u[3] = d;
            int co = (jc*32 + hi*16) ^ swl;
            short8 va0 = *(const short8*)(vb + il*128 + co);
            short8 va1 = *(const short8*)(vb + 4096 + il*128 + co);
            o0   = __builtin_amdgcn_mfma_f32_32x32x16_bf16(va0, pb.s8, o0, 0, 0, 0);
            o1   = __builtin_amdgcn_mfma_f32_32x32x16_bf16(va1, pb.s8, o1, 0, 0, 0);
            accl = __builtin_amdgcn_mfma_f32_32x32x16_bf16(ones, pb.s8, accl, 0, 0, 0);
        }
        __builtin_amdgcn_s_setprio(0);

        if (tp < 31) asm volatile("s_waitcnt vmcnt(0)" ::: "memory");  // next tile landed
        asm volatile("" ::: "memory");
        __builtin_amdgcn_s_barrier();             // single barrier per tile
        asm volatile("" ::: "memory");
        cur ^= 1;
    }
#undef STAGE_PAIR

    float l_loc = accl[0];                        // full row sum (MFMA k-dim spans both halves)

    // combine the two KV streams (each with its own max): st=1 writes, st=0 merges + outputs
    float* red = (float*)smem;                    // 256 slots x 34 floats = 34 KB (dead K/V region)
    int slot = ((qw*64 + lane) * 34);
    if (st == 1) {
        #pragma unroll
        for (int r = 0; r < 16; ++r) { red[slot + r] = o0[r]; red[slot + 16 + r] = o1[r]; }
        red[slot + 32] = l_loc;
        red[slot + 33] = m_run;
    }
    __syncthreads();
    if (st == 0) {
        float m1 = red[slot + 33], l1 = red[slot + 32];
        float m = fmaxf(m_run, m1);
        float f0 = fexp2(m_run - m), f1 = fexp2(m1 - m);
        float inv = 1.f / (l_loc * f0 + l1 * f1);
        float a0 = f0 * inv, a1 = f1 * inv;
        int b = bh >> 2, hh = bh & 3;
        int s = qbase + il;
        unsigned short* aop = &ao[((size_t)(b*4096 + s))*256 + hh*64];
        #pragma unroll
        for (int rr = 0; rr < 4; ++rr) {          // d = dt*32 + rr*8 + hi*4 + 0..3
            ushort4 pk0, pk1;
            pk0.x = f2bf(o0[rr*4+0]*a0 + red[slot + rr*4+0]*a1);
            pk0.y = f2bf(o0[rr*4+1]*a0 + red[slot + rr*4+1]*a1);
            pk0.z = f2bf(o0[rr*4+2]*a0 + red[slot + rr*4+2]*a1);
            pk0.w = f2bf(o0[rr*4+3]*a0 + red[slot + rr*4+3]*a1);
            *(ushort4*)&aop[rr*8 + hi*4] = pk0;
            pk1.x = f2bf(o1[rr*4+0]*a0 + red[slot + 16 + rr*4+0]*a1);
            pk1.y = f2bf(o1[rr*4+1]*a0 + red[slot + 16 + rr*4+1]*a1);
            pk1.z = f2bf(o1[rr*4+2]*a0 + red[slot + 16 + rr*4+2]*a1);
            pk1.w = f2bf(o1[rr*4+3]*a0 + red[slot + 16 + rr*4+3]*a1);
            *(ushort4*)&aop[32 + rr*8 + hi*4] = pk1;
        }
    }
}

// ------- out GEMM + bias + residual: block = 32 rows x 256 cols (ao fetched once) -------
__global__ __launch_bounds__(256) void k_out(
    const unsigned short* __restrict__ ao, const unsigned short* __restrict__ wT,
    const float* __restrict__ bout, const float* __restrict__ x,
    float* __restrict__ out) {
    int mt = blockIdx.x;                          // 512 blocks x 32 rows
    int tid = threadIdx.x;
    int wid = tid >> 6, lane = tid & 63;
    int g = lane >> 4, li = lane & 15;
    int rg = wid & 1, ch = wid >> 1;              // wave = 16 rows x 128 cols
    int m0 = mt * 32 + rg * 16;
    int row = m0 + li;
    f32x4 acc[8];
    #pragma unroll
    for (int nt = 0; nt < 8; ++nt) acc[nt] = (f32x4){0.f,0.f,0.f,0.f};
    #pragma unroll
    for (int kt = 0; kt < 8; ++kt) {
        short8 a = *(const short8*)&ao[row*256 + kt*32 + g*8];
        #pragma unroll
        for (int nt = 0; nt < 8; ++nt) {
            int nn = ch*128 + nt*16 + li;
            short8 b = *(const short8*)&wT[nn*256 + kt*32 + g*8];
            acc[nt] = __builtin_amdgcn_mfma_f32_16x16x32_bf16(a, b, acc[nt], 0, 0, 0);
        }
    }
    int b = m0 >> 12;
    int s0 = (m0 & 4095) + g*4;
    #pragma unroll
    for (int nt = 0; nt < 8; ++nt) {
        int c = ch*128 + nt*16 + li;
        float bias = bout[c];
        int base = (b*256 + c)*4096 + s0;
        float4 xr = *(const float4*)&x[base];
        float4 ov;
        ov.x = acc[nt][0] + bias + xr.x;
        ov.y = acc[nt][1] + bias + xr.y;
        ov.z = acc[nt][2] + bias + xr.z;
        ov.w = acc[nt][3] + bias + xr.w;
        *(float4*)&out[base] = ov;
    }
}

extern "C" void kernel_launch(void* const* d_in, const int* in_sizes, int n_in,
                              void* d_out, int out_size, void* d_ws, size_t ws_size,
                              hipStream_t stream) {
    (void)in_sizes; (void)n_in; (void)out_size; (void)ws_size;
    const float* x     = (const float*)d_in[0];
    const float* gamma = (const float*)d_in[1];
    const float* beta  = (const float*)d_in[2];
    const float* wqkv  = (const float*)d_in[3];
    const float* bqkv  = (const float*)d_in[4];
    const float* wout  = (const float*)d_in[5];
    const float* bout  = (const float*)d_in[6];
    float* out = (float*)d_out;

    char* ws = (char*)d_ws;
    unsigned short* q     = (unsigned short*)(ws + (8u<<20));         // 8 MB  [bh][S][64]
    unsigned short* kk    = (unsigned short*)(ws + (16u<<20));        // 8 MB  [bh][S][64]
    unsigned short* vT    = (unsigned short*)(ws + (24u<<20));        // 8 MB  [bh][64][S]
    unsigned short* ao    = (unsigned short*)(ws + (32u<<20));        // 8 MB  [B*S][256]
    unsigned short* wqkvT = (unsigned short*)(ws + (40u<<20));        // 384 KB [768][256]
    unsigned short* woutT = (unsigned short*)(ws + (40u<<20) + 393216);// 128 KB [256][256]
    float*          stats = (float*)(ws + (40u<<20) + 524288);        // 1 KB

    k_pre<<<320, 1024, 0, stream>>>(x, stats, wqkv, wout, wqkvT, woutT);
    k_qkvf<<<256, 512, 0, stream>>>(x, gamma, beta, stats, wqkvT, bqkv, q, kk, vT);
    k_attn<<<dim3(512), 512, 0, stream>>>(q, kk, vT, ao);
    k_out<<<dim3(512), 256, 0, stream>>>(ao, woutT, bout, x, out);
}

// Round 9
// 150.474 us; speedup vs baseline: 1.3641x; 1.1327x over previous
//
#include <hip/hip_runtime.h>
#include <hip/hip_bf16.h>

// AttentionBlock: GroupNorm -> QKV -> 4-head attention (S=4096, D=64) -> out proj -> +residual
// B=4, C=256, H=W=64, S=4096, N_GROUPS=32, N_HEADS=4, D_K=64

typedef __attribute__((ext_vector_type(8))) short short8;   // 8 bf16 (4 VGPRs) MFMA A/B frag
typedef __attribute__((ext_vector_type(4))) float f32x4;    // 16x16 MFMA C/D frag
typedef __attribute__((ext_vector_type(16))) float f32x16;  // 32x32 MFMA C/D frag

__device__ __forceinline__ unsigned short f2bf(float f) {
    union { float f; unsigned u; } v; v.f = f;
    unsigned r = v.u + 0x7FFF + ((v.u >> 16) & 1);
    return (unsigned short)(r >> 16);
}

__device__ __forceinline__ unsigned cvt_pk_bf16(float lo, float hi) {
    unsigned r;
    asm("v_cvt_pk_bf16_f32 %0, %1, %2" : "=v"(r) : "v"(lo), "v"(hi));
    return r;
}

__device__ __forceinline__ void permswap(unsigned &x, unsigned &y) {
    // x' = [x_lo | y_lo], y' = [x_hi | y_hi]   (vdst hi-half <-> vsrc lo-half)
    asm("v_permlane32_swap_b32 %0, %1" : "+v"(x), "+v"(y));
}

__device__ __forceinline__ float fexp2(float x) {   // D = 2^S0
    float r;
    asm("v_exp_f32 %0, %1" : "=v"(r) : "v"(x));
    return r;
}

__device__ __forceinline__ void gl_lds16(const void* g, void* l) {
    __builtin_amdgcn_global_load_lds(
        (const __attribute__((address_space(1))) void*)(g),
        (__attribute__((address_space(3))) void*)(l), 16, 0, 0);
}

__device__ __forceinline__ f32x16 fzero16() {
    f32x16 z;
    #pragma unroll
    for (int i = 0; i < 16; ++i) z[i] = 0.f;
    return z;
}

// -------- fat kernel: blocks 0-127 GroupNorm stats; blocks 128-319 weight convert --------
__global__ __launch_bounds__(1024) void k_pre(
    const float* __restrict__ x, float* __restrict__ stats,
    const float* __restrict__ wqkv, const float* __restrict__ wout,
    unsigned short* __restrict__ wqkvT, unsigned short* __restrict__ woutT) {
    if (blockIdx.x < 128) {
        int bg = blockIdx.x;                       // b*32+g ; group channels contiguous
        const float4* xp = (const float4*)(x + bg * 32768);
        float s1 = 0.f, s2 = 0.f;
        for (int i = threadIdx.x; i < 8192; i += 1024) {
            float4 v = xp[i];
            s1 += v.x + v.y + v.z + v.w;
            s2 += v.x*v.x + v.y*v.y + v.z*v.z + v.w*v.w;
        }
        #pragma unroll
        for (int off = 32; off; off >>= 1) {
            s1 += __shfl_down(s1, off);
            s2 += __shfl_down(s2, off);
        }
        __shared__ float r1[16], r2[16];
        int wid = threadIdx.x >> 6;
        if ((threadIdx.x & 63) == 0) { r1[wid] = s1; r2[wid] = s2; }
        __syncthreads();
        if (threadIdx.x == 0) {
            float a = 0.f, b = 0.f;
            #pragma unroll
            for (int i = 0; i < 16; ++i) { a += r1[i]; b += r2[i]; }
            float mean = a * (1.f/32768.f);
            float var  = b * (1.f/32768.f) - mean*mean;
            stats[bg*2]   = mean;
            stats[bg*2+1] = rsqrtf(var + 1e-5f);
        }
    } else {
        int i = (blockIdx.x - 128) * 1024 + threadIdx.x;
        if (i < 196608) {                       // w_qkv [256][768] -> [768][256]
            int k = i / 768, n = i - k * 768;
            wqkvT[n*256 + k] = f2bf(wqkv[i]);
        }
        if (i < 65536) {                        // w_out [256][256] -> [256][256]^T
            int k = i >> 8, n = i & 255;
            woutT[n*256 + k] = f2bf(wout[i]);
        }
    }
}

// -------- fused GroupNorm-apply + QKV GEMM --------
// block = 512 thr, 64 s-rows x all 768 outputs. Phase 1: normalize x -> bf16 h-tile in LDS.
// Phase 2: wave = 32 rows x 192 cols (cg = head), so each B-frag feeds two row-tiles
// (halves B L2 traffic vs R8). Q gets 0.125*log2(e); K plain; V transposed.
__global__ __launch_bounds__(512, 2) void k_qkvf(
    const float* __restrict__ x, const float* __restrict__ gamma,
    const float* __restrict__ beta, const float* __restrict__ stats,
    const unsigned short* __restrict__ wT, const float* __restrict__ bqkv,
    unsigned short* __restrict__ q, unsigned short* __restrict__ kk,
    unsigned short* __restrict__ vT) {
    __shared__ unsigned short t[64][72];          // c-slab staging (verified pattern)
    __shared__ unsigned short lds_h[64][272];     // h-tile [s][c], pad->bank spread

    int m0 = blockIdx.x * 64;                     // global row base (b*4096 + s0)
    int b = m0 >> 12;
    int s0 = m0 & 4095;
    int tid = threadIdx.x;

    // Phase 1: 4 slabs of 64 channels
    #pragma unroll
    for (int cb = 0; cb < 4; ++cb) {
        int c0 = cb * 64;
        #pragma unroll
        for (int k = 0; k < 2; ++k) {
            int u = tid + k * 512;                // 1024 units: 64 c x 16 float4-slots
            int cr = u >> 4;
            int sl = (u & 15) * 4;
            int c = c0 + cr;
            float4 v = *(const float4*)&x[(b*256 + c)*4096 + s0 + sl];
            int sg = (b*32 + (c >> 3)) * 2;
            float mean = stats[sg], rstd = stats[sg+1];
            float sa = rstd * gamma[c];
            float sb = beta[c] - mean * sa;
            ushort4 pk;
            pk.x = f2bf(v.x*sa + sb); pk.y = f2bf(v.y*sa + sb);
            pk.z = f2bf(v.z*sa + sb); pk.w = f2bf(v.w*sa + sb);
            *(ushort4*)&t[cr][sl] = pk;
        }
        __syncthreads();
        int sr = tid >> 3;                        // 0..63 s-row
        int cc8 = (tid & 7) * 8;                  // 8 channels per thread
        unsigned rr[4];
        #pragma unroll
        for (int j = 0; j < 4; ++j)
            rr[j] = (unsigned)t[cc8 + 2*j][sr] | ((unsigned)t[cc8 + 2*j + 1][sr] << 16);
        *(uint4*)&lds_h[sr][c0 + cc8] = make_uint4(rr[0], rr[1], rr[2], rr[3]);
        __syncthreads();
    }

    // Phase 2: GEMM 64 x 768, K=256; wave = 32 rows x 192 cols (cg = head)
    int wid = tid >> 6, lane = tid & 63;
    int g = lane >> 4, li = lane & 15;
    int rg = wid & 1, cg = wid >> 1;
    f32x4 acc[2][12];
    #pragma unroll
    for (int rt = 0; rt < 2; ++rt)
        #pragma unroll
        for (int nt = 0; nt < 12; ++nt) acc[rt][nt] = (f32x4){0.f,0.f,0.f,0.f};
    #pragma unroll
    for (int kt = 0; kt < 8; ++kt) {
        short8 a0 = *(const short8*)&lds_h[rg*32 + li][kt*32 + g*8];
        short8 a1 = *(const short8*)&lds_h[rg*32 + 16 + li][kt*32 + g*8];
        #pragma unroll
        for (int nt = 0; nt < 12; ++nt) {
            int n = cg*192 + nt*16 + li;
            short8 bb = *(const short8*)&wT[n*256 + kt*32 + g*8];
            acc[0][nt] = __builtin_amdgcn_mfma_f32_16x16x32_bf16(a0, bb, acc[0][nt], 0, 0, 0);
            acc[1][nt] = __builtin_amdgcn_mfma_f32_16x16x32_bf16(a1, bb, acc[1][nt], 0, 0, 0);
        }
    }
    int bh = b*4 + cg;
    #pragma unroll
    for (int rt = 0; rt < 2; ++rt) {
        int s0w = s0 + rg*32 + rt*16;
        #pragma unroll
        for (int nt = 0; nt < 12; ++nt) {
            int ng = cg*192 + nt*16 + li;
            float bias = bqkv[ng];
            int d = (nt & 3)*16 + li;
            if ((nt >> 2) == 2) {                     // V -> transposed [bh][d][s]
                ushort4 pk;
                pk.x = f2bf(acc[rt][nt][0] + bias); pk.y = f2bf(acc[rt][nt][1] + bias);
                pk.z = f2bf(acc[rt][nt][2] + bias); pk.w = f2bf(acc[rt][nt][3] + bias);
                *(ushort4*)&vT[(bh*64 + d)*4096 + s0w + g*4] = pk;
            } else if ((nt >> 2) == 0) {              // Q (scale 0.125*log2e folded in)
                #pragma unroll
                for (int r = 0; r < 4; ++r)
                    q[(bh*4096 + s0w + g*4 + r)*64 + d] = f2bf((acc[rt][nt][r] + bias) * 0.1803368801f);
            } else {                                  // K
                #pragma unroll
                for (int r = 0; r < 4; ++r)
                    kk[(bh*4096 + s0w + g*4 + r)*64 + d] = f2bf(acc[rt][nt][r] + bias);
            }
        }
    }
}

// ---------------- flash attention, 32x32x16 MFMA, KV-stream split -----------------------------
// Softmax: C-init = -m folds the subtract into the QK MFMA; speculative exp2 with stale max
// (bound P <= 16 via THR=4 on Pmax), rare correction; l via ones-MFMA on the matrix pipe.
__global__ __launch_bounds__(512, 4) void k_attn(
    const unsigned short* __restrict__ q, const unsigned short* __restrict__ kk,
    const unsigned short* __restrict__ vT, unsigned short* __restrict__ ao) {
    __shared__ __align__(16) char smem[65536];    // [dbuf][stream] K 8KB x4 | V 8KB x4

    int n = blockIdx.x;                           // 512 blocks; XCD = n & 7 (round-robin dispatch)
    int qt = n >> 4;
    int bh = ((n & 7) << 1) | ((n >> 3) & 1);     // 2 heads per XCD -> K/V fits 4MB L2
    int tid = threadIdx.x;
    int wid = tid >> 6, lane = tid & 63;
    int qw = wid & 3, st = wid >> 2;
    int hi = lane >> 5, il = lane & 31;
    int swl = (il & 7) << 4;

    int qbase = qt * 128 + qw * 32;
    int qrow = bh * 4096 + qbase + il;
    short8 bq[4];                                 // Q B-frags: col=il, k=kc*16+hi*8..
    #pragma unroll
    for (int kc = 0; kc < 4; ++kc)
        bq[kc] = *(const short8*)&q[qrow*64 + kc*16 + hi*8];

    short8 ones;                                  // all-ones bf16 A-frag for the l-MFMA
    #pragma unroll
    for (int i = 0; i < 8; ++i) ones[i] = (short)0x3F80;

    // staging geometry: 512 threads cover one 8KB tile (16B each)
    unsigned p16  = tid * 16;
    unsigned row0 = p16 >> 7;                     // 0..63
    unsigned sw   = (row0 & 7) << 4;
    unsigned ks0  = p16 ^ sw;                     // K tile-local swizzled source byte
    unsigned vc0  = (p16 & 127u) ^ sw;            // V column byte within row
    const char* kbase = (const char*)kk + (size_t)bh * 524288;
    const char* vbase = (const char*)vT + (size_t)(bh*64 + row0) * 8192;
    unsigned woff = wid * 1024;

#define STAGE_PAIR(d, pair) do {                                             \
    const char* _k0 = kbase + (size_t)(2*(pair)) * 8192;                     \
    size_t _vo = (size_t)(2*(pair)) * 128;                                   \
    gl_lds16(_k0 + ks0,              smem + ((d)*2+0)*8192 + woff);          \
    gl_lds16(_k0 + 8192 + ks0,       smem + ((d)*2+1)*8192 + woff);          \
    gl_lds16(vbase + _vo + vc0,       smem + 32768 + ((d)*2+0)*8192 + woff); \
    gl_lds16(vbase + _vo + 128 + vc0, smem + 32768 + ((d)*2+1)*8192 + woff); \
} while (0)

    f32x16 o0 = fzero16(), o1 = fzero16(), accl = fzero16();
    float m_run = 0.f;                            // stale-max in exp2 domain; P <= 16 guaranteed

    STAGE_PAIR(0, 0);
    asm volatile("s_waitcnt vmcnt(0)" ::: "memory");
    __builtin_amdgcn_s_barrier();
    asm volatile("" ::: "memory");

    int cur = 0;
    for (int tp = 0; tp < 32; ++tp) {
        if (tp < 31) STAGE_PAIR(cur ^ 1, tp + 1);  // issue next-tile DMA; lands during compute

        const char* kb = smem + (cur*2 + st) * 8192;
        const char* vb = smem + 32768 + (cur*2 + st) * 8192;

        // (S - m) directly out of the MFMA: C-init = -m_run
        float nm = -m_run;
        f32x16 p0, p1;
        #pragma unroll
        for (int r = 0; r < 16; ++r) { p0[r] = nm; p1[r] = nm; }
        __builtin_amdgcn_s_setprio(1);
        #pragma unroll
        for (int kc = 0; kc < 4; ++kc) {
            int c = (kc*32 + hi*16) ^ swl;
            short8 ka0 = *(const short8*)(kb + il*128 + c);
            short8 ka1 = *(const short8*)(kb + 4096 + il*128 + c);
            p0 = __builtin_amdgcn_mfma_f32_32x32x16_bf16(ka0, bq[kc], p0, 0, 0, 0);
            p1 = __builtin_amdgcn_mfma_f32_32x32x16_bf16(ka1, bq[kc], p1, 0, 0, 0);
        }
        __builtin_amdgcn_s_setprio(0);

        // speculative P = exp2(S - m_run), in place
        #pragma unroll
        for (int r = 0; r < 16; ++r) {
            p0[r] = fexp2(p0[r]);
            p1[r] = fexp2(p1[r]);
        }
        // Pmax tree (depth 5); rescale only if P would exceed 2^4
        float m8[8];
        #pragma unroll
        for (int r = 0; r < 8; ++r)
            m8[r] = fmaxf(fmaxf(p0[2*r], p0[2*r+1]), fmaxf(p1[2*r], p1[2*r+1]));
        float pm = fmaxf(fmaxf(fmaxf(m8[0], m8[1]), fmaxf(m8[2], m8[3])),
                         fmaxf(fmaxf(m8[4], m8[5]), fmaxf(m8[6], m8[7])));
        if (__any(pm > 16.f)) {                   // rare: max grew by > 4 (exp2 domain)
            pm = fmaxf(pm, __shfl_xor(pm, 32));   // row max across lane halves
            float fac = 1.f / pm;
            m_run += log2f(pm);
            accl[0] *= fac;                       // only element 0 is ever read
            #pragma unroll
            for (int r = 0; r < 16; ++r) {
                o0[r] *= fac; o1[r] *= fac;
                p0[r] *= fac; p1[r] *= fac;
            }
        }

        // pack P -> bf16 B-frags (cvt_pk + permlane32_swap) fused with PV + l MFMAs
        __builtin_amdgcn_s_setprio(1);
        #pragma unroll
        for (int jc = 0; jc < 4; ++jc) {
            const int hh = jc & 1;
            float e0, e1, e2, e3, e4, e5, e6, e7;
            if (jc < 2) {
                e0 = p0[hh*8+0]; e1 = p0[hh*8+1]; e2 = p0[hh*8+2]; e3 = p0[hh*8+3];
                e4 = p0[hh*8+4]; e5 = p0[hh*8+5]; e6 = p0[hh*8+6]; e7 = p0[hh*8+7];
            } else {
                e0 = p1[hh*8+0]; e1 = p1[hh*8+1]; e2 = p1[hh*8+2]; e3 = p1[hh*8+3];
                e4 = p1[hh*8+4]; e5 = p1[hh*8+5]; e6 = p1[hh*8+6]; e7 = p1[hh*8+7];
            }
            unsigned a = cvt_pk_bf16(e0, e1);
            unsigned b = cvt_pk_bf16(e2, e3);
            unsigned c = cvt_pk_bf16(e4, e5);
            unsigned d = cvt_pk_bf16(e6, e7);
            permswap(a, c);                       // -> [a_lo|c_lo], [a_hi|c_hi]
            permswap(b, d);
            union { unsigned u[4]; short8 s8; } pb;
            pb.u[0] = a; pb.u[1] = b; pb.u[2] = c; pb.u[3] = d;
            int co = (jc*32 + hi*16) ^ swl;
            short8 va0 = *(const short8*)(vb + il*128 + co);
            short8 va1 = *(const short8*)(vb + 4096 + il*128 + co);
            o0   = __builtin_amdgcn_mfma_f32_32x32x16_bf16(va0, pb.s8, o0, 0, 0, 0);
            o1   = __builtin_amdgcn_mfma_f32_32x32x16_bf16(va1, pb.s8, o1, 0, 0, 0);
            accl = __builtin_amdgcn_mfma_f32_32x32x16_bf16(ones, pb.s8, accl, 0, 0, 0);
        }
        __builtin_amdgcn_s_setprio(0);

        if (tp < 31) asm volatile("s_waitcnt vmcnt(0)" ::: "memory");  // next tile landed
        asm volatile("" ::: "memory");
        __builtin_amdgcn_s_barrier();             // single barrier per tile
        asm volatile("" ::: "memory");
        cur ^= 1;
    }
#undef STAGE_PAIR

    float l_loc = accl[0];                        // full row sum (MFMA k-dim spans both halves)

    // combine the two KV streams (each with its own max): st=1 writes, st=0 merges + outputs
    float* red = (float*)smem;                    // 256 slots x 34 floats = 34 KB (dead K/V region)
    int slot = ((qw*64 + lane) * 34);
    if (st == 1) {
        #pragma unroll
        for (int r = 0; r < 16; ++r) { red[slot + r] = o0[r]; red[slot + 16 + r] = o1[r]; }
        red[slot + 32] = l_loc;
        red[slot + 33] = m_run;
    }
    __syncthreads();
    if (st == 0) {
        float m1 = red[slot + 33], l1 = red[slot + 32];
        float m = fmaxf(m_run, m1);
        float f0 = fexp2(m_run - m), f1 = fexp2(m1 - m);
        float inv = 1.f / (l_loc * f0 + l1 * f1);
        float a0 = f0 * inv, a1 = f1 * inv;
        int b = bh >> 2, hh = bh & 3;
        int s = qbase + il;
        unsigned short* aop = &ao[((size_t)(b*4096 + s))*256 + hh*64];
        #pragma unroll
        for (int rr = 0; rr < 4; ++rr) {          // d = dt*32 + rr*8 + hi*4 + 0..3
            ushort4 pk0, pk1;
            pk0.x = f2bf(o0[rr*4+0]*a0 + red[slot + rr*4+0]*a1);
            pk0.y = f2bf(o0[rr*4+1]*a0 + red[slot + rr*4+1]*a1);
            pk0.z = f2bf(o0[rr*4+2]*a0 + red[slot + rr*4+2]*a1);
            pk0.w = f2bf(o0[rr*4+3]*a0 + red[slot + rr*4+3]*a1);
            *(ushort4*)&aop[rr*8 + hi*4] = pk0;
            pk1.x = f2bf(o1[rr*4+0]*a0 + red[slot + 16 + rr*4+0]*a1);
            pk1.y = f2bf(o1[rr*4+1]*a0 + red[slot + 16 + rr*4+1]*a1);
            pk1.z = f2bf(o1[rr*4+2]*a0 + red[slot + 16 + rr*4+2]*a1);
            pk1.w = f2bf(o1[rr*4+3]*a0 + red[slot + 16 + rr*4+3]*a1);
            *(ushort4*)&aop[32 + rr*8 + hi*4] = pk1;
        }
    }
}

// ------- out GEMM + bias + residual: 64 rows x 256 cols per block, coalesced epilogue -------
// MFMA accs staged (with bias) into a transposed LDS tile [c][s]; x-read / out-write then
// fully coalesced float4 along s.
__global__ __launch_bounds__(512) void k_out(
    const unsigned short* __restrict__ ao, const unsigned short* __restrict__ wT,
    const float* __restrict__ bout, const float* __restrict__ x,
    float* __restrict__ out) {
    __shared__ float lds_fT[256][68];             // [c][s+pad]: 69.6 KB, rows 16B-aligned
    int mt = blockIdx.x;                          // 256 blocks x 64 rows
    int tid = threadIdx.x;
    int wid = tid >> 6, lane = tid & 63;
    int g = lane >> 4, li = lane & 15;
    int rg = wid & 3, ch = wid >> 2;              // wave = 16 rows x 128 cols
    int m0 = mt * 64;
    int row = m0 + rg*16 + li;
    f32x4 acc[8];
    #pragma unroll
    for (int nt = 0; nt < 8; ++nt) acc[nt] = (f32x4){0.f,0.f,0.f,0.f};
    #pragma unroll
    for (int kt = 0; kt < 8; ++kt) {
        short8 a = *(const short8*)&ao[row*256 + kt*32 + g*8];
        #pragma unroll
        for (int nt = 0; nt < 8; ++nt) {
            int nn = ch*128 + nt*16 + li;
            short8 b = *(const short8*)&wT[nn*256 + kt*32 + g*8];
            acc[nt] = __builtin_amdgcn_mfma_f32_16x16x32_bf16(a, b, acc[nt], 0, 0, 0);
        }
    }
    #pragma unroll
    for (int nt = 0; nt < 8; ++nt) {
        int c = ch*128 + nt*16 + li;
        float bias = bout[c];
        #pragma unroll
        for (int r = 0; r < 4; ++r)
            lds_fT[c][rg*16 + g*4 + r] = acc[nt][r] + bias;
    }
    __syncthreads();
    int b = m0 >> 12;
    int s0 = m0 & 4095;
    #pragma unroll
    for (int p = 0; p < 8; ++p) {
        int c = p*32 + (tid >> 4);
        int sl = (tid & 15) * 4;
        float4 t = *(const float4*)&lds_fT[c][sl];
        int base = (b*256 + c)*4096 + s0 + sl;
        float4 xr = *(const float4*)&x[base];
        t.x += xr.x; t.y += xr.y; t.z += xr.z; t.w += xr.w;
        *(float4*)&out[base] = t;
    }
}

extern "C" void kernel_launch(void* const* d_in, const int* in_sizes, int n_in,
                              void* d_out, int out_size, void* d_ws, size_t ws_size,
                              hipStream_t stream) {
    (void)in_sizes; (void)n_in; (void)out_size; (void)ws_size;
    const float* x     = (const float*)d_in[0];
    const float* gamma = (const float*)d_in[1];
    const float* beta  = (const float*)d_in[2];
    const float* wqkv  = (const float*)d_in[3];
    const float* bqkv  = (const float*)d_in[4];
    const float* wout  = (const float*)d_in[5];
    const float* bout  = (const float*)d_in[6];
    float* out = (float*)d_out;

    char* ws = (char*)d_ws;
    unsigned short* q     = (unsigned short*)(ws + (8u<<20));         // 8 MB  [bh][S][64]
    unsigned short* kk    = (unsigned short*)(ws + (16u<<20));        // 8 MB  [bh][S][64]
    unsigned short* vT    = (unsigned short*)(ws + (24u<<20));        // 8 MB  [bh][64][S]
    unsigned short* ao    = (unsigned short*)(ws + (32u<<20));        // 8 MB  [B*S][256]
    unsigned short* wqkvT = (unsigned short*)(ws + (40u<<20));        // 384 KB [768][256]
    unsigned short* woutT = (unsigned short*)(ws + (40u<<20) + 393216);// 128 KB [256][256]
    float*          stats = (float*)(ws + (40u<<20) + 524288);        // 1 KB

    k_pre<<<320, 1024, 0, stream>>>(x, stats, wqkv, wout, wqkvT, woutT);
    k_qkvf<<<256, 512, 0, stream>>>(x, gamma, beta, stats, wqkvT, bqkv, q, kk, vT);
    k_attn<<<dim3(512), 512, 0, stream>>>(q, kk, vT, ao);
    k_out<<<dim3(256), 512, 0, stream>>>(ao, woutT, bout, x, out);
}